// Round 14
// baseline (227.858 us; speedup 1.0000x reference)
//
#include <hip/hip_runtime.h>
#include <hip/hip_bf16.h>
#include <stdint.h>

#define BATCH 4
#define NPTS  1024
#define CIN   512
#define NS    32
#define P_TOT (BATCH*NPTS*NS)      /* 131072 */
#define CO    512
#define RADIUS_F 0.05f
#define HMIN_F  (-0.02f)
#define HMAX_F  (0.04f)

typedef __attribute__((ext_vector_type(8))) short short8;
typedef __attribute__((ext_vector_type(4))) float f32x4;

__device__ __forceinline__ unsigned short f2bf(float f) {
  unsigned int x = __float_as_uint(f);
  x = x + 0x7fffu + ((x >> 16) & 1u);   // RNE
  return (unsigned short)(x >> 16);
}
__device__ __forceinline__ float bf2f(unsigned short u) {
  return __uint_as_float(((unsigned int)u) << 16);
}
__device__ __forceinline__ unsigned int cvtpk(float lo, float hi) {
  unsigned int r;
  asm("v_cvt_pk_bf16_f32 %0, %1, %2" : "=v"(r) : "v"(lo), "v"(hi));
  return r;   // D[15:0]=bf16(lo), D[31:16]=bf16(hi), RNE
}
__device__ __forceinline__ void load_lds16(const void* g, void* l) {
  __builtin_amdgcn_global_load_lds((const __attribute__((address_space(1))) void*)g,
                                   (__attribute__((address_space(3))) void*)l, 16, 0, 0);
}

// ---------------- cylinder query + fused scatter -----------------------------
// Writes idx, lxyz; accumulates L4[u]=(Σl,cnt) and GM[9] global moments.
__global__ void cyl_query_kernel(const float* __restrict__ xyz,
                                 const float* __restrict__ rot,
                                 int* __restrict__ idxout,
                                 float* __restrict__ lxyz,
                                 float* __restrict__ L4,
                                 float* __restrict__ GM) {
  int bm = blockIdx.x;             // b*1024 + m
  int b = bm >> 10;
  int lane = threadIdx.x;          // 64 threads = 1 wave
  const float* ctr = xyz + (size_t)bm * 3;
  float cx = ctr[0], cy = ctr[1], cz = ctr[2];
  const float* R = rot + (size_t)bm * 9;
  float r00=R[0],r01=R[1],r02=R[2],r10=R[3],r11=R[4],r12=R[5],r20=R[6],r21=R[7],r22=R[8];
  __shared__ int sidx[32];
  int taken = 0;
  for (int base = 0; base < NPTS && taken < NS; base += 64) {
    int n = base + lane;
    const float* p = xyz + ((size_t)b * NPTS + n) * 3;
    float dx = p[0]-cx, dy = p[1]-cy, dz = p[2]-cz;
    float rx = dx*r00 + dy*r10 + dz*r20;
    float ry = dx*r01 + dy*r11 + dz*r21;
    float rz = dx*r02 + dy*r12 + dz*r22;
    bool ok = (ry*ry + rz*rz < RADIUS_F*RADIUS_F) && (rx > HMIN_F) && (rx < HMAX_F);
    unsigned long long bal = __ballot(ok);
    if (ok) {
      int slot = taken + __popcll(bal & ((1ull << lane) - 1ull));
      if (slot < NS) sidx[slot] = n;
    }
    taken += __popcll(bal);
  }
  __syncthreads();
  int filled = taken < NS ? taken : NS;
  float m[9] = {0.f,0.f,0.f,0.f,0.f,0.f,0.f,0.f,0.f};
  if (lane < NS) {
    int nsel = (lane < filled) ? sidx[lane] : sidx[0];
    size_t pp = (size_t)bm * NS + lane;
    idxout[pp] = nsel;
    const float* pn = xyz + ((size_t)b * NPTS + nsel) * 3;
    float dx = pn[0]-cx, dy = pn[1]-cy, dz = pn[2]-cz;
    const float inv = 1.0f / RADIUS_F;
    float rx = (dx*r00 + dy*r10 + dz*r20) * inv;
    float ry = (dx*r01 + dy*r11 + dz*r21) * inv;
    float rz = (dx*r02 + dy*r12 + dz*r22) * inv;
    float* lw = lxyz + pp * 3;
    lw[0] = rx; lw[1] = ry; lw[2] = rz;
    // fused scatter: per-unique-row sums (padding duplicates count, as in ref)
    float* dst = L4 + (((size_t)b << 10) + nsel)*4;
    atomicAdd(dst+0, rx); atomicAdd(dst+1, ry);
    atomicAdd(dst+2, rz); atomicAdd(dst+3, 1.0f);
    m[0]=rx; m[1]=ry; m[2]=rz;
    m[3]=rx*rx; m[4]=rx*ry; m[5]=rx*rz; m[6]=ry*ry; m[7]=ry*rz; m[8]=rz*rz;
  }
  // all 64 lanes participate (lanes >= NS contribute zeros)
  #pragma unroll
  for (int d = 1; d < 64; d <<= 1)
    #pragma unroll
    for (int e = 0; e < 9; ++e) m[e] += __shfl_xor(m[e], d);
  if (lane < 9) atomicAdd(&GM[lane], m[lane]);
}

// ---------------- transpose feats (B,C,N) fp32 -> (B,N,C) bf16 --------------
__global__ void transpose_feats(const float* __restrict__ feats,
                                unsigned short* __restrict__ featsT) {
  __shared__ float tile[64][65];
  int b = blockIdx.z, cb = blockIdx.y, nb = blockIdx.x;
  int t = threadIdx.x, tr = t >> 6, tc = t & 63;
  #pragma unroll
  for (int j = 0; j < 16; ++j) {
    int c = cb*64 + j*4 + tr;
    tile[j*4+tr][tc] = feats[((size_t)b*CIN + c)*NPTS + nb*64 + tc];
  }
  __syncthreads();
  #pragma unroll
  for (int j = 0; j < 16; ++j) {
    int n = nb*64 + j*4 + tr;
    featsT[((size_t)b*NPTS + n)*CIN + cb*64 + tc] = f2bf(tile[tc][j*4+tr]);
  }
}

// ---------------- weight conversion (merged) --------------------------------
__global__ void build_weights(const float* __restrict__ W1,
                              const float* __restrict__ W2,
                              unsigned short* __restrict__ w1f,
                              float* __restrict__ w1l,
                              unsigned short* __restrict__ w2b) {
  int i = blockIdx.x*256 + threadIdx.x;
  if (i < 512*512) {
    int o = i >> 9, k = i & 511;
    w1f[i] = f2bf(W1[o*515 + 3 + k]);
    w2b[i] = f2bf(W2[i]);
  }
  if (i < 512*3) {
    w1l[i] = W1[(i/3)*515 + (i%3)];
  }
}

// ============ GEMM1u: unique-point features x W1f^T (fp32 out) ==============
__global__ __launch_bounds__(256) void gemm1u_kernel(
    const unsigned short* __restrict__ A,
    const unsigned short* __restrict__ Bw,
    float* __restrict__ C)
{
  __shared__ unsigned short As[128*32];
  __shared__ unsigned short Bs[128*32];
  int bx = blockIdx.x;
  int ob = bx & 3;
  size_t p0 = (size_t)(bx >> 2) * 128;
  int o0 = ob * 128;
  int t = threadIdx.x;
  int w = t >> 6, lane = t & 63;
  int wr = w >> 1, wc = w & 1;
  int l15 = lane & 15, l4 = lane >> 4;
  f32x4 acc[4][4];
  f32x4 zf = {0.f, 0.f, 0.f, 0.f};
  #pragma unroll
  for (int mi = 0; mi < 4; ++mi)
    #pragma unroll
    for (int ni = 0; ni < 4; ++ni) acc[mi][ni] = zf;

  int c0 = 2*w;
  int srow = lane >> 2;
  int scole = (lane & 3) * 8;

  const unsigned short* abase[2];
  const unsigned short* bbase[2];
  #pragma unroll
  for (int cc = 0; cc < 2; ++cc) {
    int row = 16*(c0+cc) + srow;
    abase[cc] = A + (p0 + row)*(size_t)512 + scole;
    bbase[cc] = Bw + (size_t)(o0 + row)*512 + scole;
  }

  for (int k0 = 0; k0 < 512; k0 += 32) {
    #pragma unroll
    for (int cc = 0; cc < 2; ++cc) {
      int c = c0 + cc;
      load_lds16(abase[cc] + k0, (char*)As + c*1024);
      load_lds16(bbase[cc] + k0, (char*)Bs + c*1024);
    }
    __syncthreads();
    short8 af[4], bfr[4];
    #pragma unroll
    for (int mi = 0; mi < 4; ++mi)
      af[mi] = *(const short8*)(As + (wr*64 + mi*16 + l15)*32 + l4*8);
    #pragma unroll
    for (int ni = 0; ni < 4; ++ni)
      bfr[ni] = *(const short8*)(Bs + (wc*64 + ni*16 + l15)*32 + l4*8);
    #pragma unroll
    for (int mi = 0; mi < 4; ++mi)
      #pragma unroll
      for (int ni = 0; ni < 4; ++ni)
        acc[mi][ni] = __builtin_amdgcn_mfma_f32_16x16x32_bf16(af[mi], bfr[ni], acc[mi][ni], 0, 0, 0);
    __syncthreads();
  }
  #pragma unroll
  for (int mi = 0; mi < 4; ++mi)
    #pragma unroll
    for (int ni = 0; ni < 4; ++ni)
      #pragma unroll
      for (int j = 0; j < 4; ++j) {
        size_t p = p0 + wr*64 + mi*16 + l4*4 + j;
        int o = o0 + wc*64 + ni*16 + l15;
        C[p*512 + o] = acc[mi][ni][j];
      }
}

// ============ stats1: algebraic BN1 sums over u (one h1u read) ==============
__global__ __launch_bounds__(256) void stats1_kernel(
    const float* __restrict__ h1u, const float* __restrict__ L4,
    const float* __restrict__ w1l, float* __restrict__ sums) {
  int t = threadIdx.x;
  int c2 = t*2;
  int u0 = blockIdx.x * 16;
  float w0a = w1l[c2*3],     w1a = w1l[c2*3+1],     w2a = w1l[c2*3+2];
  float w0b = w1l[(c2+1)*3], w1b = w1l[(c2+1)*3+1], w2b = w1l[(c2+1)*3+2];
  float s0=0.f, s1=0.f, q0=0.f, q1=0.f;
  #pragma unroll 4
  for (int j = 0; j < 16; ++j) {
    int u = u0 + j;
    float4 Lc = *(const float4*)(L4 + (size_t)u*4);
    float2 h = *(const float2*)(h1u + (size_t)u*512 + c2);
    float lwa = Lc.x*w0a + Lc.y*w1a + Lc.z*w2a;
    float lwb = Lc.x*w0b + Lc.y*w1b + Lc.z*w2b;
    s0 += Lc.w*h.x;  q0 += Lc.w*h.x*h.x + 2.f*h.x*lwa;
    s1 += Lc.w*h.y;  q1 += Lc.w*h.y*h.y + 2.f*h.y*lwb;
  }
  atomicAdd(&sums[c2],       s0);
  atomicAdd(&sums[c2+1],     s1);
  atomicAdd(&sums[512+c2],   q0);
  atomicAdd(&sums[512+c2+1], q1);
}

// ---- finalize1: BN1 scale/shift + folded local weights w1ls = sc*w1l -------
__global__ void finalize1_kernel(const float* __restrict__ sums,
                                 const float* __restrict__ GM,
                                 const float* __restrict__ w1l,
                                 const float* __restrict__ g,
                                 const float* __restrict__ bia,
                                 float* __restrict__ ss,
                                 float* __restrict__ w1ls) {
  int c = blockIdx.x*256 + threadIdx.x;
  if (c >= 512) return;
  float w0 = w1l[c*3], w1 = w1l[c*3+1], w2 = w1l[c*3+2];
  float S = sums[c] + w0*GM[0] + w1*GM[1] + w2*GM[2];
  float Q = sums[512+c] + w0*w0*GM[3] + 2.f*w0*w1*GM[4] + 2.f*w0*w2*GM[5]
                        + w1*w1*GM[6] + 2.f*w1*w2*GM[7] + w2*w2*GM[8];
  const float invN = 1.f / (float)P_TOT;
  float mean = S * invN;
  float var  = Q * invN - mean*mean;
  float sc = g[c] * rsqrtf(var + 1e-5f);
  ss[c] = sc;
  ss[512+c] = bia[c] - mean*sc;
  w1ls[c]        = sc * w0;   // planar [3][512]
  w1ls[512 + c]  = sc * w1;
  w1ls[1024 + c] = sc * w2;
}

// ---- fold: h1u <- sc*h1u + sh (in place; BN1 affine folded into operand) ---
__global__ __launch_bounds__(256) void fold_kernel(float* __restrict__ h1u,
                                                   const float* __restrict__ ss) {
  size_t i = ((size_t)blockIdx.x*256 + threadIdx.x) * 4;   // 2048 blocks
  int c = (int)(i & 511);
  float4 v = *(float4*)(h1u + i);
  float4 sc = *(const float4*)(ss + c);
  float4 sh = *(const float4*)(ss + 512 + c);
  v.x = fmaf(v.x, sc.x, sh.x);
  v.y = fmaf(v.y, sc.y, sh.y);
  v.z = fmaf(v.z, sc.z, sh.z);
  v.w = fmaf(v.w, sc.w, sh.w);
  *(float4*)(h1u + i) = v;
}

__global__ void finalize_kernel(const float* __restrict__ sums,
                                const float* __restrict__ g,
                                const float* __restrict__ bia,
                                float* __restrict__ ss) {
  int c = blockIdx.x*256 + threadIdx.x;
  if (c >= 512) return;
  const float invN = 1.f / (float)P_TOT;
  float mean = sums[c] * invN;
  float var  = sums[512+c] * invN - mean*mean;
  float sc = g[c] * rsqrtf(var + 1e-5f);
  ss[c] = sc;
  ss[512+c] = bia[c] - mean*sc;
}

// ============ GEMM2 (r12-exact): 128x256 tile, 8 waves (2x4), swizzled LDS ==
__global__ __launch_bounds__(512) void gemm2_kernel(
    const float* __restrict__ h1u,    // (4096, 512) f32 FOLDED
    const int* __restrict__ idx,      // (P)
    const float* __restrict__ lxyz,   // (P, 3)
    const float* __restrict__ w1ls,   // [3][512] folded local weights
    const unsigned short* __restrict__ Bw,    // (512, 512) bf16
    float* __restrict__ sums,                 // BN2 stats
    float* __restrict__ pmax,                 // (4096, 512)
    float* __restrict__ pmin)
{
  __shared__ unsigned short As[128*32];    // 8 KB
  __shared__ unsigned short Bs[256*32];    // 16 KB
  __shared__ float wl[1536];               // 6 KB
  int bx = blockIdx.x;
  int ob = bx & 1;
  size_t p0 = (size_t)(bx >> 1) * 128;
  int o0 = ob * 256;
  int t = threadIdx.x;                     // 512 threads = 8 waves
  int w = t >> 6, lane = t & 63;
  int wr = w >> 2;                         // 0..1 (p dim)
  int wc = w & 3;                          // 0..3 (o dim)
  int l15 = lane & 15, l4 = lane >> 4;
  f32x4 acc[4][4];
  f32x4 zf = {0.f, 0.f, 0.f, 0.f};
  #pragma unroll
  for (int mi = 0; mi < 4; ++mi)
    #pragma unroll
    for (int ni = 0; ni < 4; ++ni) acc[mi][ni] = zf;

  int sl = (lane & 3) ^ ((lane >> 3) & 3);   // swizzled 16B slot
  int scole = (lane & 3) * 8;
  int cA = (l4 ^ ((l15 >> 1) & 3)) * 8;      // swizzled read elem offset

  // wl: planar [3][512]
  wl[t] = w1ls[t]; wl[512 + t] = w1ls[512 + t]; wl[1024 + t] = w1ls[1024 + t];

  // A: one 16-row chunk per wave (chunk = w); per lane: row = 16w + (lane>>2)
  int arow = 16*w + (lane >> 2);
  int awoff = arow*64 + sl*16;               // swizzled As write byte offset
  const float* hptr;
  float lxr, lyr, lzr;
  {
    size_t p = p0 + arow;
    int b = (int)(p >> 15);
    int n = idx[p];
    hptr = h1u + (((size_t)b << 10) + n)*512 + scole;
    const float* lwp = lxyz + p*3;
    lxr = lwp[0]; lyr = lwp[1]; lzr = lwp[2];
  }
  // B: two 16-row chunks per wave (c = 2w+cc); pre-swizzled global source
  const unsigned short* bptr[2];
  #pragma unroll
  for (int cc = 0; cc < 2; ++cc) {
    int brow = 16*(2*w + cc) + (lane >> 2);
    bptr[cc] = Bw + (size_t)(o0 + brow)*CIN + sl*8;
  }

  float4 hv0 = *(const float4*)(hptr);
  float4 hv1 = *(const float4*)(hptr + 4);
  __syncthreads();   // wl staged

  for (int k0 = 0; k0 < CIN; k0 += 32) {
    #pragma unroll
    for (int cc = 0; cc < 2; ++cc)
      load_lds16(bptr[cc] + k0, (char*)Bs + (2*w + cc)*1024);   // linear dest
    // folded local-weight tables for channels k0+scole..+7
    int ch0 = k0 + scole;
    float4 xa = *(const float4*)(wl + ch0);
    float4 xb = *(const float4*)(wl + ch0 + 4);
    float4 ya = *(const float4*)(wl + 512 + ch0);
    float4 yb = *(const float4*)(wl + 512 + ch0 + 4);
    float4 za = *(const float4*)(wl + 1024 + ch0);
    float4 zb = *(const float4*)(wl + 1024 + ch0 + 4);
    float w0[8] = {xa.x,xa.y,xa.z,xa.w,xb.x,xb.y,xb.z,xb.w};
    float w1[8] = {ya.x,ya.y,ya.z,ya.w,yb.x,yb.y,yb.z,yb.w};
    float w2[8] = {za.x,za.y,za.z,za.w,zb.x,zb.y,zb.z,zb.w};
    {
      float fv[8] = {hv0.x, hv0.y, hv0.z, hv0.w, hv1.x, hv1.y, hv1.z, hv1.w};
      float gv[8];
      #pragma unroll
      for (int e = 0; e < 8; ++e)
        gv[e] = fmaxf(fv[e] + lxr*w0[e] + lyr*w1[e] + lzr*w2[e], 0.f);
      unsigned int rv[4];
      #pragma unroll
      for (int j = 0; j < 4; ++j) rv[j] = cvtpk(gv[2*j], gv[2*j+1]);
      *(uint4*)((char*)As + awoff) = make_uint4(rv[0], rv[1], rv[2], rv[3]);
    }
    if (k0 + 32 < CIN) {
      hv0 = *(const float4*)(hptr + k0 + 32);
      hv1 = *(const float4*)(hptr + k0 + 36);
    }
    __syncthreads();
    short8 af[4], bfr[4];
    #pragma unroll
    for (int mi = 0; mi < 4; ++mi)
      af[mi] = *(const short8*)(As + (wr*64 + mi*16 + l15)*32 + cA);
    #pragma unroll
    for (int ni = 0; ni < 4; ++ni)
      bfr[ni] = *(const short8*)(Bs + (wc*64 + ni*16 + l15)*32 + cA);
    #pragma unroll
    for (int mi = 0; mi < 4; ++mi)
      #pragma unroll
      for (int ni = 0; ni < 4; ++ni)
        acc[mi][ni] = __builtin_amdgcn_mfma_f32_16x16x32_bf16(af[mi], bfr[ni], acc[mi][ni], 0, 0, 0);
    __syncthreads();
  }

  #pragma unroll
  for (int ni = 0; ni < 4; ++ni) {
    float s = 0.f, q = 0.f;
    #pragma unroll
    for (int mi = 0; mi < 4; ++mi)
      #pragma unroll
      for (int j = 0; j < 4; ++j) { float v = acc[mi][ni][j]; s += v; q += v*v; }
    s += __shfl_xor(s, 16); q += __shfl_xor(q, 16);
    s += __shfl_xor(s, 32); q += __shfl_xor(q, 32);
    if (l4 == 0) {
      int c = o0 + wc*64 + ni*16 + l15;
      atomicAdd(&sums[c], s);
      atomicAdd(&sums[512 + c], q);
    }
  }
  #pragma unroll
  for (int ni = 0; ni < 4; ++ni) {
    #pragma unroll
    for (int h = 0; h < 2; ++h) {
      float mx = -3.4e38f, mn = 3.4e38f;
      #pragma unroll
      for (int mi = 2*h; mi < 2*h + 2; ++mi)
        #pragma unroll
        for (int j = 0; j < 4; ++j) {
          float v = acc[mi][ni][j];
          mx = fmaxf(mx, v); mn = fminf(mn, v);
        }
      mx = fmaxf(mx, __shfl_xor(mx, 16)); mn = fminf(mn, __shfl_xor(mn, 16));
      mx = fmaxf(mx, __shfl_xor(mx, 32)); mn = fminf(mn, __shfl_xor(mn, 32));
      if (l4 == 0) {
        size_t bm = (p0 >> 5) + 2*wr + h;
        int o = o0 + wc*64 + ni*16 + l15;
        pmax[bm*512 + o] = mx;
        pmin[bm*512 + o] = mn;
      }
    }
  }
}

// ---------------- final: affine+relu on pooled, transpose to (B,512,M) ------
__global__ void final_transpose(const float* __restrict__ pmax,
                                const float* __restrict__ pmin,
                                const float* __restrict__ ss,
                                float* __restrict__ out) {
  __shared__ float tile[64][65];
  int b = blockIdx.z, ob = blockIdx.y, mb = blockIdx.x;
  int t = threadIdx.x, tr = t >> 6, tc = t & 63;
  #pragma unroll
  for (int j = 0; j < 16; ++j) {
    int m = mb*64 + j*4 + tr;
    int o = ob*64 + tc;
    float sc = ss[o], sh = ss[512+o];
    size_t pi = (((size_t)b << 10) + m)*512 + o;
    float v = (sc >= 0.f) ? pmax[pi] : pmin[pi];
    tile[j*4+tr][tc] = fmaxf(fmaf(v, sc, sh), 0.f);
  }
  __syncthreads();
  #pragma unroll
  for (int j = 0; j < 16; ++j) {
    int o = ob*64 + j*4 + tr;
    out[((size_t)b*512 + o)*1024 + mb*64 + tc] = tile[tc][j*4+tr];
  }
}

extern "C" void kernel_launch(void* const* d_in, const int* in_sizes, int n_in,
                              void* d_out, int out_size, void* d_ws, size_t ws_size,
                              hipStream_t stream) {
  const float* xyz   = (const float*)d_in[0];
  const float* feats = (const float*)d_in[1];
  const float* rot   = (const float*)d_in[2];
  const float* W1    = (const float*)d_in[3];
  const float* g1    = (const float*)d_in[4];
  const float* b1    = (const float*)d_in[5];
  const float* W2    = (const float*)d_in[6];
  const float* g2    = (const float*)d_in[7];
  const float* b2    = (const float*)d_in[8];
  float* out = (float*)d_out;
  char* wsb = (char*)d_ws;

  const size_t OFF_IDX    = 0;                                          // 512 KB
  const size_t OFF_LXYZ   = OFF_IDX    + (size_t)P_TOT*4;               // 1.5 MB
  const size_t OFF_FEATST = OFF_LXYZ   + (size_t)P_TOT*3*4;             // 4.2 MB
  const size_t OFF_W1F    = OFF_FEATST + (size_t)BATCH*NPTS*CIN*2;      // 512 KB
  const size_t OFF_W1L    = OFF_W1F    + (size_t)CO*512*2;              // 8 KB
  const size_t OFF_W1LS   = OFF_W1L    + 8192;                          // 8 KB
  const size_t OFF_W2B    = OFF_W1LS   + 8192;                          // 512 KB
  const size_t OFF_STATS  = OFF_W2B    + (size_t)CO*CIN*2;              // 16 KB
  const size_t OFF_L4     = OFF_STATS  + 16384;                         // 64 KB
  const size_t OFF_GM     = OFF_L4     + 65536;                         // 4 KB
  const size_t OFF_H1U    = OFF_GM     + 4096;                          // 8 MB
  const size_t OFF_PMAX   = OFF_H1U    + (size_t)BATCH*NPTS*CO*4;       // 8 MB
  const size_t OFF_PMIN   = OFF_PMAX   + (size_t)BATCH*NPTS*CO*4;       // 8 MB
  const size_t WS_NEED    = OFF_PMIN   + (size_t)BATCH*NPTS*CO*4;       // ~31 MiB

  if (ws_size < WS_NEED) return;   // diagnostic guard

  int* idx             = (int*)(wsb + OFF_IDX);
  float* lxyz          = (float*)(wsb + OFF_LXYZ);
  unsigned short* fT   = (unsigned short*)(wsb + OFF_FEATST);
  unsigned short* w1f  = (unsigned short*)(wsb + OFF_W1F);
  float* w1l           = (float*)(wsb + OFF_W1L);
  float* w1ls          = (float*)(wsb + OFF_W1LS);
  unsigned short* w2b  = (unsigned short*)(wsb + OFF_W2B);
  float* stats         = (float*)(wsb + OFF_STATS);
  float* sums1 = stats;
  float* ss1   = stats + 1024;
  float* sums2 = stats + 2048;
  float* ss2   = stats + 3072;
  float* L4            = (float*)(wsb + OFF_L4);
  float* GM            = (float*)(wsb + OFF_GM);
  float* h1u           = (float*)(wsb + OFF_H1U);
  float* pmax          = (float*)(wsb + OFF_PMAX);
  float* pmin          = (float*)(wsb + OFF_PMIN);

  hipMemsetAsync(stats, 0, 16384 + 65536 + 4096, stream);

  transpose_feats<<<dim3(NPTS/64, CIN/64, BATCH), 256, 0, stream>>>(feats, fT);
  build_weights<<<(512*512 + 255)/256, 256, 0, stream>>>(W1, W2, w1f, w1l, w2b);
  cyl_query_kernel<<<BATCH*NPTS, 64, 0, stream>>>(xyz, rot, idx, lxyz, L4, GM);

  gemm1u_kernel<<<(BATCH*NPTS/128)*4, 256, 0, stream>>>(fT, w1f, h1u);
  stats1_kernel<<<256, 256, 0, stream>>>(h1u, L4, w1l, sums1);
  finalize1_kernel<<<2, 256, 0, stream>>>(sums1, GM, w1l, g1, b1, ss1, w1ls);
  fold_kernel<<<(BATCH*NPTS*CO/4)/256, 256, 0, stream>>>(h1u, ss1);

  gemm2_kernel<<<(P_TOT/128)*2, 512, 0, stream>>>(h1u, idx, lxyz, w1ls, w2b,
                                                  sums2, pmax, pmin);
  finalize_kernel<<<2, 256, 0, stream>>>(sums2, g2, b2, ss2);

  final_transpose<<<dim3(NPTS/64, CO/64, BATCH), 256, 0, stream>>>(pmax, pmin, ss2, out);
}

// Round 15
// 213.541 us; speedup vs baseline: 1.0670x; 1.0670x over previous
//
#include <hip/hip_runtime.h>
#include <hip/hip_bf16.h>
#include <stdint.h>

#define BATCH 4
#define NPTS  1024
#define CIN   512
#define NS    32
#define P_TOT (BATCH*NPTS*NS)      /* 131072 */
#define CO    512
#define RADIUS_F 0.05f
#define HMIN_F  (-0.02f)
#define HMAX_F  (0.04f)

typedef __attribute__((ext_vector_type(8))) short short8;
typedef __attribute__((ext_vector_type(4))) float f32x4;

__device__ __forceinline__ unsigned short f2bf(float f) {
  unsigned int x = __float_as_uint(f);
  x = x + 0x7fffu + ((x >> 16) & 1u);   // RNE
  return (unsigned short)(x >> 16);
}
__device__ __forceinline__ float bf2f(unsigned short u) {
  return __uint_as_float(((unsigned int)u) << 16);
}
__device__ __forceinline__ unsigned int cvtpk(float lo, float hi) {
  unsigned int r;
  asm("v_cvt_pk_bf16_f32 %0, %1, %2" : "=v"(r) : "v"(lo), "v"(hi));
  return r;   // D[15:0]=bf16(lo), D[31:16]=bf16(hi), RNE
}
__device__ __forceinline__ void load_lds16(const void* g, void* l) {
  __builtin_amdgcn_global_load_lds((const __attribute__((address_space(1))) void*)g,
                                   (__attribute__((address_space(3))) void*)l, 16, 0, 0);
}

// ---------------- cylinder query: idx + local coords (f32) ------------------
__global__ void cyl_query_kernel(const float* __restrict__ xyz,
                                 const float* __restrict__ rot,
                                 int* __restrict__ idxout,
                                 float* __restrict__ lxyz) {
  int bm = blockIdx.x;             // b*1024 + m
  int b = bm >> 10;
  int lane = threadIdx.x;          // 64 threads = 1 wave
  const float* ctr = xyz + (size_t)bm * 3;
  float cx = ctr[0], cy = ctr[1], cz = ctr[2];
  const float* R = rot + (size_t)bm * 9;
  float r00=R[0],r01=R[1],r02=R[2],r10=R[3],r11=R[4],r12=R[5],r20=R[6],r21=R[7],r22=R[8];
  __shared__ int sidx[32];
  int taken = 0;
  for (int base = 0; base < NPTS && taken < NS; base += 64) {
    int n = base + lane;
    const float* p = xyz + ((size_t)b * NPTS + n) * 3;
    float dx = p[0]-cx, dy = p[1]-cy, dz = p[2]-cz;
    float rx = dx*r00 + dy*r10 + dz*r20;
    float ry = dx*r01 + dy*r11 + dz*r21;
    float rz = dx*r02 + dy*r12 + dz*r22;
    bool ok = (ry*ry + rz*rz < RADIUS_F*RADIUS_F) && (rx > HMIN_F) && (rx < HMAX_F);
    unsigned long long bal = __ballot(ok);
    if (ok) {
      int slot = taken + __popcll(bal & ((1ull << lane) - 1ull));
      if (slot < NS) sidx[slot] = n;
    }
    taken += __popcll(bal);
  }
  __syncthreads();
  int filled = taken < NS ? taken : NS;
  if (lane < NS) {
    int nsel = (lane < filled) ? sidx[lane] : sidx[0];
    size_t pp = (size_t)bm * NS + lane;
    idxout[pp] = nsel;
    const float* pn = xyz + ((size_t)b * NPTS + nsel) * 3;
    float dx = pn[0]-cx, dy = pn[1]-cy, dz = pn[2]-cz;
    const float inv = 1.0f / RADIUS_F;
    float rx = (dx*r00 + dy*r10 + dz*r20) * inv;
    float ry = (dx*r01 + dy*r11 + dz*r21) * inv;
    float rz = (dx*r02 + dy*r12 + dz*r22) * inv;
    float* lw = lxyz + pp * 3;
    lw[0] = rx; lw[1] = ry; lw[2] = rz;
  }
}

// ---------------- transpose feats (B,C,N) fp32 -> (B,N,C) bf16 --------------
__global__ void transpose_feats(const float* __restrict__ feats,
                                unsigned short* __restrict__ featsT) {
  __shared__ float tile[64][65];
  int b = blockIdx.z, cb = blockIdx.y, nb = blockIdx.x;
  int t = threadIdx.x, tr = t >> 6, tc = t & 63;
  #pragma unroll
  for (int j = 0; j < 16; ++j) {
    int c = cb*64 + j*4 + tr;
    tile[j*4+tr][tc] = feats[((size_t)b*CIN + c)*NPTS + nb*64 + tc];
  }
  __syncthreads();
  #pragma unroll
  for (int j = 0; j < 16; ++j) {
    int n = nb*64 + j*4 + tr;
    featsT[((size_t)b*NPTS + n)*CIN + cb*64 + tc] = f2bf(tile[tc][j*4+tr]);
  }
}

// ---------------- weight conversion (merged) --------------------------------
__global__ void build_weights(const float* __restrict__ W1,
                              const float* __restrict__ W2,
                              unsigned short* __restrict__ w1f,
                              float* __restrict__ w1l,
                              unsigned short* __restrict__ w2b) {
  int i = blockIdx.x*256 + threadIdx.x;
  if (i < 512*512) {
    int o = i >> 9, k = i & 511;
    w1f[i] = f2bf(W1[o*515 + 3 + k]);
    w2b[i] = f2bf(W2[i]);
  }
  if (i < 512*3) {
    w1l[i] = W1[(i/3)*515 + (i%3)];
  }
}

// ============ scatter: per-unique-row local sums + counts + global moments ===
__global__ __launch_bounds__(256) void scatter_kernel(
    const int* __restrict__ idx, const float* __restrict__ lxyz,
    float* __restrict__ L4, float* __restrict__ GM) {
  int i = blockIdx.x*256 + threadIdx.x;   // 512 blocks x 256 = P_TOT
  int b = i >> 15;
  int n = idx[i];
  const float* lw = lxyz + (size_t)i*3;
  float lx = lw[0], ly = lw[1], lz = lw[2];
  float* dst = L4 + (((size_t)b << 10) + n)*4;
  atomicAdd(dst+0, lx); atomicAdd(dst+1, ly);
  atomicAdd(dst+2, lz); atomicAdd(dst+3, 1.0f);
  float m[9] = {lx, ly, lz, lx*lx, lx*ly, lx*lz, ly*ly, ly*lz, lz*lz};
  #pragma unroll
  for (int d = 1; d < 64; d <<= 1)
    #pragma unroll
    for (int e = 0; e < 9; ++e) m[e] += __shfl_xor(m[e], d);
  __shared__ float mred[9];
  if (threadIdx.x < 9) mred[threadIdx.x] = 0.f;
  __syncthreads();
  if ((threadIdx.x & 63) == 0)
    #pragma unroll
    for (int e = 0; e < 9; ++e) atomicAdd(&mred[e], m[e]);
  __syncthreads();
  if (threadIdx.x < 9) atomicAdd(&GM[threadIdx.x], mred[threadIdx.x]);
}

// ============ GEMM1u: unique features x W1f^T + fused BN1 stats =============
__global__ __launch_bounds__(256) void gemm1u_kernel(
    const unsigned short* __restrict__ A,
    const unsigned short* __restrict__ Bw,
    float* __restrict__ C,
    const float* __restrict__ L4,     // (4096,4) per-u local sums + cnt
    const float* __restrict__ w1l,    // (512,3)
    float* __restrict__ sums)         // BN1 sums
{
  __shared__ unsigned short As[128*32];
  __shared__ unsigned short Bs[128*32];
  int bx = blockIdx.x;
  int ob = bx & 3;
  size_t p0 = (size_t)(bx >> 2) * 128;
  int o0 = ob * 128;
  int t = threadIdx.x;
  int w = t >> 6, lane = t & 63;
  int wr = w >> 1, wc = w & 1;
  int l15 = lane & 15, l4 = lane >> 4;
  f32x4 acc[4][4];
  f32x4 zf = {0.f, 0.f, 0.f, 0.f};
  #pragma unroll
  for (int mi = 0; mi < 4; ++mi)
    #pragma unroll
    for (int ni = 0; ni < 4; ++ni) acc[mi][ni] = zf;

  int c0 = 2*w;
  int srow = lane >> 2;
  int scole = (lane & 3) * 8;

  const unsigned short* abase[2];
  const unsigned short* bbase[2];
  #pragma unroll
  for (int cc = 0; cc < 2; ++cc) {
    int row = 16*(c0+cc) + srow;
    abase[cc] = A + (p0 + row)*(size_t)512 + scole;
    bbase[cc] = Bw + (size_t)(o0 + row)*512 + scole;
  }

  for (int k0 = 0; k0 < 512; k0 += 32) {
    #pragma unroll
    for (int cc = 0; cc < 2; ++cc) {
      int c = c0 + cc;
      load_lds16(abase[cc] + k0, (char*)As + c*1024);
      load_lds16(bbase[cc] + k0, (char*)Bs + c*1024);
    }
    __syncthreads();
    short8 af[4], bfr[4];
    #pragma unroll
    for (int mi = 0; mi < 4; ++mi)
      af[mi] = *(const short8*)(As + (wr*64 + mi*16 + l15)*32 + l4*8);
    #pragma unroll
    for (int ni = 0; ni < 4; ++ni)
      bfr[ni] = *(const short8*)(Bs + (wc*64 + ni*16 + l15)*32 + l4*8);
    #pragma unroll
    for (int mi = 0; mi < 4; ++mi)
      #pragma unroll
      for (int ni = 0; ni < 4; ++ni)
        acc[mi][ni] = __builtin_amdgcn_mfma_f32_16x16x32_bf16(af[mi], bfr[ni], acc[mi][ni], 0, 0, 0);
    __syncthreads();
  }
  // C store (fp32 h1u, RAW)
  #pragma unroll
  for (int mi = 0; mi < 4; ++mi)
    #pragma unroll
    for (int ni = 0; ni < 4; ++ni)
      #pragma unroll
      for (int j = 0; j < 4; ++j) {
        size_t p = p0 + wr*64 + mi*16 + l4*4 + j;
        int o = o0 + wc*64 + ni*16 + l15;
        C[p*512 + o] = acc[mi][ni][j];
      }
  // fused BN1 stats: S_c += cnt*h ; Q_c += cnt*h^2 + 2h*(L·w_c)
  #pragma unroll
  for (int ni = 0; ni < 4; ++ni) {
    int c = o0 + wc*64 + ni*16 + l15;
    float wa = w1l[c*3], wb = w1l[c*3+1], wcc = w1l[c*3+2];
    float s = 0.f, q = 0.f;
    #pragma unroll
    for (int mi = 0; mi < 4; ++mi)
      #pragma unroll
      for (int j = 0; j < 4; ++j) {
        size_t p = p0 + wr*64 + mi*16 + l4*4 + j;
        float4 L = *(const float4*)(L4 + p*4);
        float h = acc[mi][ni][j];
        float lw = L.x*wa + L.y*wb + L.z*wcc;
        s += L.w*h;
        q += L.w*h*h + 2.f*h*lw;
      }
    s += __shfl_xor(s, 16); q += __shfl_xor(q, 16);
    s += __shfl_xor(s, 32); q += __shfl_xor(q, 32);
    if (l4 == 0) {
      atomicAdd(&sums[c], s);
      atomicAdd(&sums[512 + c], q);
    }
  }
}

// ---- finalize1: BN1 scale/shift + folded local weights w1ls = sc*w1l -------
__global__ void finalize1_kernel(const float* __restrict__ sums,
                                 const float* __restrict__ GM,
                                 const float* __restrict__ w1l,
                                 const float* __restrict__ g,
                                 const float* __restrict__ bia,
                                 float* __restrict__ ss,
                                 float* __restrict__ w1ls) {
  int c = blockIdx.x*256 + threadIdx.x;
  if (c >= 512) return;
  float w0 = w1l[c*3], w1 = w1l[c*3+1], w2 = w1l[c*3+2];
  float S = sums[c] + w0*GM[0] + w1*GM[1] + w2*GM[2];
  float Q = sums[512+c] + w0*w0*GM[3] + 2.f*w0*w1*GM[4] + 2.f*w0*w2*GM[5]
                        + w1*w1*GM[6] + 2.f*w1*w2*GM[7] + w2*w2*GM[8];
  const float invN = 1.f / (float)P_TOT;
  float mean = S * invN;
  float var  = Q * invN - mean*mean;
  float sc = g[c] * rsqrtf(var + 1e-5f);
  ss[c] = sc;
  ss[512+c] = bia[c] - mean*sc;
  w1ls[c]        = sc * w0;   // planar [3][512]
  w1ls[512 + c]  = sc * w1;
  w1ls[1024 + c] = sc * w2;
}

// ============ GEMM2: 128x256 tile, 8 waves, swizzled LDS, fused BN1-fold ====
// A = relu(fma(h_raw, sc, sh) + l·w1ls) -> bf16  (identical chain to fold+r12)
__global__ __launch_bounds__(512) void gemm2_kernel(
    const float* __restrict__ h1u,    // (4096, 512) f32 RAW
    const int* __restrict__ idx,      // (P)
    const float* __restrict__ lxyz,   // (P, 3)
    const float* __restrict__ w1ls,   // [3][512] folded local weights
    const float* __restrict__ ss,     // BN1 scale/shift (1024 f32)
    const unsigned short* __restrict__ Bw,    // (512, 512) bf16
    float* __restrict__ sums,                 // BN2 stats
    float* __restrict__ pmax,                 // (4096, 512)
    float* __restrict__ pmin)
{
  __shared__ unsigned short As[128*32];    // 8 KB
  __shared__ unsigned short Bs[256*32];    // 16 KB
  __shared__ float wl[1536];               // 6 KB
  __shared__ float ssl[1024];              // 4 KB
  int bx = blockIdx.x;
  int ob = bx & 1;
  size_t p0 = (size_t)(bx >> 1) * 128;
  int o0 = ob * 256;
  int t = threadIdx.x;                     // 512 threads = 8 waves
  int w = t >> 6, lane = t & 63;
  int wr = w >> 2;                         // 0..1 (p dim)
  int wc = w & 3;                          // 0..3 (o dim)
  int l15 = lane & 15, l4 = lane >> 4;
  f32x4 acc[4][4];
  f32x4 zf = {0.f, 0.f, 0.f, 0.f};
  #pragma unroll
  for (int mi = 0; mi < 4; ++mi)
    #pragma unroll
    for (int ni = 0; ni < 4; ++ni) acc[mi][ni] = zf;

  int sl = (lane & 3) ^ ((lane >> 3) & 3);   // swizzled 16B slot
  int scole = (lane & 3) * 8;
  int cA = (l4 ^ ((l15 >> 1) & 3)) * 8;      // swizzled read elem offset

  // tables: wl planar [3][512], ssl [sc|sh]
  wl[t] = w1ls[t]; wl[512 + t] = w1ls[512 + t]; wl[1024 + t] = w1ls[1024 + t];
  ssl[t] = ss[t]; ssl[512 + t] = ss[512 + t];

  int arow = 16*w + (lane >> 2);
  int awoff = arow*64 + sl*16;               // swizzled As write byte offset
  const float* hptr;
  float lxr, lyr, lzr;
  {
    size_t p = p0 + arow;
    int b = (int)(p >> 15);
    int n = idx[p];
    hptr = h1u + (((size_t)b << 10) + n)*512 + scole;
    const float* lwp = lxyz + p*3;
    lxr = lwp[0]; lyr = lwp[1]; lzr = lwp[2];
  }
  const unsigned short* bptr[2];
  #pragma unroll
  for (int cc = 0; cc < 2; ++cc) {
    int brow = 16*(2*w + cc) + (lane >> 2);
    bptr[cc] = Bw + (size_t)(o0 + brow)*CIN + sl*8;
  }

  float4 hv0 = *(const float4*)(hptr);
  float4 hv1 = *(const float4*)(hptr + 4);
  __syncthreads();   // tables staged

  for (int k0 = 0; k0 < CIN; k0 += 32) {
    #pragma unroll
    for (int cc = 0; cc < 2; ++cc)
      load_lds16(bptr[cc] + k0, (char*)Bs + (2*w + cc)*1024);   // linear dest
    int ch0 = k0 + scole;
    float4 xa = *(const float4*)(wl + ch0);
    float4 xb = *(const float4*)(wl + ch0 + 4);
    float4 ya = *(const float4*)(wl + 512 + ch0);
    float4 yb = *(const float4*)(wl + 512 + ch0 + 4);
    float4 za = *(const float4*)(wl + 1024 + ch0);
    float4 zb = *(const float4*)(wl + 1024 + ch0 + 4);
    float4 sA = *(const float4*)(ssl + ch0);
    float4 sB = *(const float4*)(ssl + ch0 + 4);
    float4 hA = *(const float4*)(ssl + 512 + ch0);
    float4 hB = *(const float4*)(ssl + 512 + ch0 + 4);
    float w0[8] = {xa.x,xa.y,xa.z,xa.w,xb.x,xb.y,xb.z,xb.w};
    float w1[8] = {ya.x,ya.y,ya.z,ya.w,yb.x,yb.y,yb.z,yb.w};
    float w2[8] = {za.x,za.y,za.z,za.w,zb.x,zb.y,zb.z,zb.w};
    float sc_[8] = {sA.x,sA.y,sA.z,sA.w,sB.x,sB.y,sB.z,sB.w};
    float sh_[8] = {hA.x,hA.y,hA.z,hA.w,hB.x,hB.y,hB.z,hB.w};
    {
      float hvr[8] = {hv0.x, hv0.y, hv0.z, hv0.w, hv1.x, hv1.y, hv1.z, hv1.w};
      float gv[8];
      #pragma unroll
      for (int e = 0; e < 8; ++e) {
        float fv = fmaf(hvr[e], sc_[e], sh_[e]);          // = fold
        gv[e] = fmaxf(fv + lxr*w0[e] + lyr*w1[e] + lzr*w2[e], 0.f);
      }
      unsigned int rv[4];
      #pragma unroll
      for (int j = 0; j < 4; ++j) rv[j] = cvtpk(gv[2*j], gv[2*j+1]);
      *(uint4*)((char*)As + awoff) = make_uint4(rv[0], rv[1], rv[2], rv[3]);
    }
    if (k0 + 32 < CIN) {
      hv0 = *(const float4*)(hptr + k0 + 32);
      hv1 = *(const float4*)(hptr + k0 + 36);
    }
    __syncthreads();
    short8 af[4], bfr[4];
    #pragma unroll
    for (int mi = 0; mi < 4; ++mi)
      af[mi] = *(const short8*)(As + (wr*64 + mi*16 + l15)*32 + cA);
    #pragma unroll
    for (int ni = 0; ni < 4; ++ni)
      bfr[ni] = *(const short8*)(Bs + (wc*64 + ni*16 + l15)*32 + cA);
    #pragma unroll
    for (int mi = 0; mi < 4; ++mi)
      #pragma unroll
      for (int ni = 0; ni < 4; ++ni)
        acc[mi][ni] = __builtin_amdgcn_mfma_f32_16x16x32_bf16(af[mi], bfr[ni], acc[mi][ni], 0, 0, 0);
    __syncthreads();
  }

  #pragma unroll
  for (int ni = 0; ni < 4; ++ni) {
    float s = 0.f, q = 0.f;
    #pragma unroll
    for (int mi = 0; mi < 4; ++mi)
      #pragma unroll
      for (int j = 0; j < 4; ++j) { float v = acc[mi][ni][j]; s += v; q += v*v; }
    s += __shfl_xor(s, 16); q += __shfl_xor(q, 16);
    s += __shfl_xor(s, 32); q += __shfl_xor(q, 32);
    if (l4 == 0) {
      int c = o0 + wc*64 + ni*16 + l15;
      atomicAdd(&sums[c], s);
      atomicAdd(&sums[512 + c], q);
    }
  }
  #pragma unroll
  for (int ni = 0; ni < 4; ++ni) {
    #pragma unroll
    for (int h = 0; h < 2; ++h) {
      float mx = -3.4e38f, mn = 3.4e38f;
      #pragma unroll
      for (int mi = 2*h; mi < 2*h + 2; ++mi)
        #pragma unroll
        for (int j = 0; j < 4; ++j) {
          float v = acc[mi][ni][j];
          mx = fmaxf(mx, v); mn = fminf(mn, v);
        }
      mx = fmaxf(mx, __shfl_xor(mx, 16)); mn = fminf(mn, __shfl_xor(mn, 16));
      mx = fmaxf(mx, __shfl_xor(mx, 32)); mn = fminf(mn, __shfl_xor(mn, 32));
      if (l4 == 0) {
        size_t bm = (p0 >> 5) + 2*wr + h;
        int o = o0 + wc*64 + ni*16 + l15;
        pmax[bm*512 + o] = mx;
        pmin[bm*512 + o] = mn;
      }
    }
  }
}

// -------- final: BN2 finalize (per block) + affine+relu + transpose ---------
__global__ void final_transpose(const float* __restrict__ pmax,
                                const float* __restrict__ pmin,
                                const float* __restrict__ sums,
                                const float* __restrict__ g,
                                const float* __restrict__ bia,
                                float* __restrict__ out) {
  __shared__ float tile[64][65];
  __shared__ float scl[64], shl[64];
  int b = blockIdx.z, ob = blockIdx.y, mb = blockIdx.x;
  int t = threadIdx.x, tr = t >> 6, tc = t & 63;
  if (t < 64) {
    int c = ob*64 + t;
    const float invN = 1.f / (float)P_TOT;
    float mean = sums[c] * invN;
    float var  = sums[512+c] * invN - mean*mean;
    float sc = g[c] * rsqrtf(var + 1e-5f);
    scl[t] = sc;
    shl[t] = bia[c] - mean*sc;
  }
  __syncthreads();
  #pragma unroll
  for (int j = 0; j < 16; ++j) {
    int m = mb*64 + j*4 + tr;
    float sc = scl[tc], sh = shl[tc];
    size_t pi = (((size_t)b << 10) + m)*512 + ob*64 + tc;
    float v = (sc >= 0.f) ? pmax[pi] : pmin[pi];
    tile[j*4+tr][tc] = fmaxf(fmaf(v, sc, sh), 0.f);
  }
  __syncthreads();
  #pragma unroll
  for (int j = 0; j < 16; ++j) {
    int o = ob*64 + j*4 + tr;
    out[((size_t)b*512 + o)*1024 + mb*64 + tc] = tile[tc][j*4+tr];
  }
}

extern "C" void kernel_launch(void* const* d_in, const int* in_sizes, int n_in,
                              void* d_out, int out_size, void* d_ws, size_t ws_size,
                              hipStream_t stream) {
  const float* xyz   = (const float*)d_in[0];
  const float* feats = (const float*)d_in[1];
  const float* rot   = (const float*)d_in[2];
  const float* W1    = (const float*)d_in[3];
  const float* g1    = (const float*)d_in[4];
  const float* b1    = (const float*)d_in[5];
  const float* W2    = (const float*)d_in[6];
  const float* g2    = (const float*)d_in[7];
  const float* b2    = (const float*)d_in[8];
  float* out = (float*)d_out;
  char* wsb = (char*)d_ws;

  const size_t OFF_IDX    = 0;                                          // 512 KB
  const size_t OFF_LXYZ   = OFF_IDX    + (size_t)P_TOT*4;               // 1.5 MB
  const size_t OFF_FEATST = OFF_LXYZ   + (size_t)P_TOT*3*4;             // 4.2 MB
  const size_t OFF_W1F    = OFF_FEATST + (size_t)BATCH*NPTS*CIN*2;      // 512 KB
  const size_t OFF_W1L    = OFF_W1F    + (size_t)CO*512*2;              // 8 KB
  const size_t OFF_W1LS   = OFF_W1L    + 8192;                          // 8 KB
  const size_t OFF_W2B    = OFF_W1LS   + 8192;                          // 512 KB
  const size_t OFF_STATS  = OFF_W2B    + (size_t)CO*CIN*2;              // 16 KB
  const size_t OFF_L4     = OFF_STATS  + 16384;                         // 64 KB
  const size_t OFF_GM     = OFF_L4     + 65536;                         // 4 KB
  const size_t OFF_H1U    = OFF_GM     + 4096;                          // 8 MB
  const size_t OFF_PMAX   = OFF_H1U    + (size_t)BATCH*NPTS*CO*4;       // 8 MB
  const size_t OFF_PMIN   = OFF_PMAX   + (size_t)BATCH*NPTS*CO*4;       // 8 MB
  const size_t WS_NEED    = OFF_PMIN   + (size_t)BATCH*NPTS*CO*4;       // ~31 MiB

  if (ws_size < WS_NEED) return;   // diagnostic guard

  int* idx             = (int*)(wsb + OFF_IDX);
  float* lxyz          = (float*)(wsb + OFF_LXYZ);
  unsigned short* fT   = (unsigned short*)(wsb + OFF_FEATST);
  unsigned short* w1f  = (unsigned short*)(wsb + OFF_W1F);
  float* w1l           = (float*)(wsb + OFF_W1L);
  float* w1ls          = (float*)(wsb + OFF_W1LS);
  unsigned short* w2b  = (unsigned short*)(wsb + OFF_W2B);
  float* stats         = (float*)(wsb + OFF_STATS);
  float* sums1 = stats;
  float* ss1   = stats + 1024;
  float* sums2 = stats + 2048;
  float* L4            = (float*)(wsb + OFF_L4);
  float* GM            = (float*)(wsb + OFF_GM);
  float* h1u           = (float*)(wsb + OFF_H1U);
  float* pmax          = (float*)(wsb + OFF_PMAX);
  float* pmin          = (float*)(wsb + OFF_PMIN);

  hipMemsetAsync(stats, 0, 16384 + 65536 + 4096, stream);

  transpose_feats<<<dim3(NPTS/64, CIN/64, BATCH), 256, 0, stream>>>(feats, fT);
  build_weights<<<(512*512 + 255)/256, 256, 0, stream>>>(W1, W2, w1f, w1l, w2b);
  cyl_query_kernel<<<BATCH*NPTS, 64, 0, stream>>>(xyz, rot, idx, lxyz);
  scatter_kernel<<<P_TOT/256, 256, 0, stream>>>(idx, lxyz, L4, GM);

  gemm1u_kernel<<<(BATCH*NPTS/128)*4, 256, 0, stream>>>(fT, w1f, h1u, L4, w1l, sums1);
  finalize1_kernel<<<2, 256, 0, stream>>>(sums1, GM, w1l, g1, b1, ss1, w1ls);

  gemm2_kernel<<<(P_TOT/128)*2, 512, 0, stream>>>(h1u, idx, lxyz, w1ls, ss1, w2b,
                                                  sums2, pmax, pmin);

  final_transpose<<<dim3(NPTS/64, CO/64, BATCH), 256, 0, stream>>>(pmax, pmin,
                                                                   sums2, g2, b2, out);
}

// Round 16
// 197.533 us; speedup vs baseline: 1.1535x; 1.0810x over previous
//
#include <hip/hip_runtime.h>
#include <hip/hip_bf16.h>
#include <stdint.h>

#define BATCH 4
#define NPTS  1024
#define CIN   512
#define NS    32
#define P_TOT (BATCH*NPTS*NS)      /* 131072 */
#define CO    512
#define RADIUS_F 0.05f
#define HMIN_F  (-0.02f)
#define HMAX_F  (0.04f)

typedef __attribute__((ext_vector_type(8))) short short8;
typedef __attribute__((ext_vector_type(4))) float f32x4;

__device__ __forceinline__ unsigned short f2bf(float f) {
  unsigned int x = __float_as_uint(f);
  x = x + 0x7fffu + ((x >> 16) & 1u);   // RNE
  return (unsigned short)(x >> 16);
}
__device__ __forceinline__ float bf2f(unsigned short u) {
  return __uint_as_float(((unsigned int)u) << 16);
}
__device__ __forceinline__ unsigned int cvtpk(float lo, float hi) {
  unsigned int r;
  asm("v_cvt_pk_bf16_f32 %0, %1, %2" : "=v"(r) : "v"(lo), "v"(hi));
  return r;   // D[15:0]=bf16(lo), D[31:16]=bf16(hi), RNE
}
__device__ __forceinline__ void load_lds16(const void* g, void* l) {
  __builtin_amdgcn_global_load_lds((const __attribute__((address_space(1))) void*)g,
                                   (__attribute__((address_space(3))) void*)l, 16, 0, 0);
}

// ---------------- cylinder query: idx + local coords (f32) ------------------
__global__ void cyl_query_kernel(const float* __restrict__ xyz,
                                 const float* __restrict__ rot,
                                 int* __restrict__ idxout,
                                 float* __restrict__ lxyz) {
  int bm = blockIdx.x;             // b*1024 + m
  int b = bm >> 10;
  int lane = threadIdx.x;          // 64 threads = 1 wave
  const float* ctr = xyz + (size_t)bm * 3;
  float cx = ctr[0], cy = ctr[1], cz = ctr[2];
  const float* R = rot + (size_t)bm * 9;
  float r00=R[0],r01=R[1],r02=R[2],r10=R[3],r11=R[4],r12=R[5],r20=R[6],r21=R[7],r22=R[8];
  __shared__ int sidx[32];
  int taken = 0;
  for (int base = 0; base < NPTS && taken < NS; base += 64) {
    int n = base + lane;
    const float* p = xyz + ((size_t)b * NPTS + n) * 3;
    float dx = p[0]-cx, dy = p[1]-cy, dz = p[2]-cz;
    float rx = dx*r00 + dy*r10 + dz*r20;
    float ry = dx*r01 + dy*r11 + dz*r21;
    float rz = dx*r02 + dy*r12 + dz*r22;
    bool ok = (ry*ry + rz*rz < RADIUS_F*RADIUS_F) && (rx > HMIN_F) && (rx < HMAX_F);
    unsigned long long bal = __ballot(ok);
    if (ok) {
      int slot = taken + __popcll(bal & ((1ull << lane) - 1ull));
      if (slot < NS) sidx[slot] = n;
    }
    taken += __popcll(bal);
  }
  __syncthreads();
  int filled = taken < NS ? taken : NS;
  if (lane < NS) {
    int nsel = (lane < filled) ? sidx[lane] : sidx[0];
    size_t pp = (size_t)bm * NS + lane;
    idxout[pp] = nsel;
    const float* pn = xyz + ((size_t)b * NPTS + nsel) * 3;
    float dx = pn[0]-cx, dy = pn[1]-cy, dz = pn[2]-cz;
    const float inv = 1.0f / RADIUS_F;
    float rx = (dx*r00 + dy*r10 + dz*r20) * inv;
    float ry = (dx*r01 + dy*r11 + dz*r21) * inv;
    float rz = (dx*r02 + dy*r12 + dz*r22) * inv;
    float* lw = lxyz + pp * 3;
    lw[0] = rx; lw[1] = ry; lw[2] = rz;
  }
}

// ---------------- transpose feats (B,C,N) fp32 -> (B,N,C) bf16 --------------
__global__ void transpose_feats(const float* __restrict__ feats,
                                unsigned short* __restrict__ featsT) {
  __shared__ float tile[64][65];
  int b = blockIdx.z, cb = blockIdx.y, nb = blockIdx.x;
  int t = threadIdx.x, tr = t >> 6, tc = t & 63;
  #pragma unroll
  for (int j = 0; j < 16; ++j) {
    int c = cb*64 + j*4 + tr;
    tile[j*4+tr][tc] = feats[((size_t)b*CIN + c)*NPTS + nb*64 + tc];
  }
  __syncthreads();
  #pragma unroll
  for (int j = 0; j < 16; ++j) {
    int n = nb*64 + j*4 + tr;
    featsT[((size_t)b*NPTS + n)*CIN + cb*64 + tc] = f2bf(tile[tc][j*4+tr]);
  }
}

// ---------------- weight conversion (merged) --------------------------------
__global__ void build_weights(const float* __restrict__ W1,
                              const float* __restrict__ W2,
                              unsigned short* __restrict__ w1f,
                              float* __restrict__ w1l,
                              unsigned short* __restrict__ w2b) {
  int i = blockIdx.x*256 + threadIdx.x;
  if (i < 512*512) {
    int o = i >> 9, k = i & 511;
    w1f[i] = f2bf(W1[o*515 + 3 + k]);
    w2b[i] = f2bf(W2[i]);
  }
  if (i < 512*3) {
    w1l[i] = W1[(i/3)*515 + (i%3)];
  }
}

// ============ scatter: per-unique-row local sums + counts + global moments ===
__global__ __launch_bounds__(256) void scatter_kernel(
    const int* __restrict__ idx, const float* __restrict__ lxyz,
    float* __restrict__ L4, float* __restrict__ GM) {
  int i = blockIdx.x*256 + threadIdx.x;   // 512 blocks x 256 = P_TOT
  int b = i >> 15;
  int n = idx[i];
  const float* lw = lxyz + (size_t)i*3;
  float lx = lw[0], ly = lw[1], lz = lw[2];
  float* dst = L4 + (((size_t)b << 10) + n)*4;
  atomicAdd(dst+0, lx); atomicAdd(dst+1, ly);
  atomicAdd(dst+2, lz); atomicAdd(dst+3, 1.0f);
  float m[9] = {lx, ly, lz, lx*lx, lx*ly, lx*lz, ly*ly, ly*lz, lz*lz};
  #pragma unroll
  for (int d = 1; d < 64; d <<= 1)
    #pragma unroll
    for (int e = 0; e < 9; ++e) m[e] += __shfl_xor(m[e], d);
  __shared__ float mred[9];
  if (threadIdx.x < 9) mred[threadIdx.x] = 0.f;
  __syncthreads();
  if ((threadIdx.x & 63) == 0)
    #pragma unroll
    for (int e = 0; e < 9; ++e) atomicAdd(&mred[e], m[e]);
  __syncthreads();
  if (threadIdx.x < 9) atomicAdd(&GM[threadIdx.x], mred[threadIdx.x]);
}

// ============ GEMM1u: unique features x W1f^T + fused BN1 stats =============
__global__ __launch_bounds__(256) void gemm1u_kernel(
    const unsigned short* __restrict__ A,
    const unsigned short* __restrict__ Bw,
    float* __restrict__ C,
    const float* __restrict__ L4,     // (4096,4) per-u local sums + cnt
    const float* __restrict__ w1l,    // (512,3)
    float* __restrict__ sums)         // BN1 sums
{
  __shared__ unsigned short As[128*32];
  __shared__ unsigned short Bs[128*32];
  int bx = blockIdx.x;
  int ob = bx & 3;
  size_t p0 = (size_t)(bx >> 2) * 128;
  int o0 = ob * 128;
  int t = threadIdx.x;
  int w = t >> 6, lane = t & 63;
  int wr = w >> 1, wc = w & 1;
  int l15 = lane & 15, l4 = lane >> 4;
  f32x4 acc[4][4];
  f32x4 zf = {0.f, 0.f, 0.f, 0.f};
  #pragma unroll
  for (int mi = 0; mi < 4; ++mi)
    #pragma unroll
    for (int ni = 0; ni < 4; ++ni) acc[mi][ni] = zf;

  int c0 = 2*w;
  int srow = lane >> 2;
  int scole = (lane & 3) * 8;

  const unsigned short* abase[2];
  const unsigned short* bbase[2];
  #pragma unroll
  for (int cc = 0; cc < 2; ++cc) {
    int row = 16*(c0+cc) + srow;
    abase[cc] = A + (p0 + row)*(size_t)512 + scole;
    bbase[cc] = Bw + (size_t)(o0 + row)*512 + scole;
  }

  for (int k0 = 0; k0 < 512; k0 += 32) {
    #pragma unroll
    for (int cc = 0; cc < 2; ++cc) {
      int c = c0 + cc;
      load_lds16(abase[cc] + k0, (char*)As + c*1024);
      load_lds16(bbase[cc] + k0, (char*)Bs + c*1024);
    }
    __syncthreads();
    short8 af[4], bfr[4];
    #pragma unroll
    for (int mi = 0; mi < 4; ++mi)
      af[mi] = *(const short8*)(As + (wr*64 + mi*16 + l15)*32 + l4*8);
    #pragma unroll
    for (int ni = 0; ni < 4; ++ni)
      bfr[ni] = *(const short8*)(Bs + (wc*64 + ni*16 + l15)*32 + l4*8);
    #pragma unroll
    for (int mi = 0; mi < 4; ++mi)
      #pragma unroll
      for (int ni = 0; ni < 4; ++ni)
        acc[mi][ni] = __builtin_amdgcn_mfma_f32_16x16x32_bf16(af[mi], bfr[ni], acc[mi][ni], 0, 0, 0);
    __syncthreads();
  }
  // C store (fp32 h1u, RAW)
  #pragma unroll
  for (int mi = 0; mi < 4; ++mi)
    #pragma unroll
    for (int ni = 0; ni < 4; ++ni)
      #pragma unroll
      for (int j = 0; j < 4; ++j) {
        size_t p = p0 + wr*64 + mi*16 + l4*4 + j;
        int o = o0 + wc*64 + ni*16 + l15;
        C[p*512 + o] = acc[mi][ni][j];
      }
  // fused BN1 stats: S_c += cnt*h ; Q_c += cnt*h^2 + 2h*(L·w_c)
  #pragma unroll
  for (int ni = 0; ni < 4; ++ni) {
    int c = o0 + wc*64 + ni*16 + l15;
    float wa = w1l[c*3], wb = w1l[c*3+1], wcc = w1l[c*3+2];
    float s = 0.f, q = 0.f;
    #pragma unroll
    for (int mi = 0; mi < 4; ++mi)
      #pragma unroll
      for (int j = 0; j < 4; ++j) {
        size_t p = p0 + wr*64 + mi*16 + l4*4 + j;
        float4 L = *(const float4*)(L4 + p*4);
        float h = acc[mi][ni][j];
        float lw = L.x*wa + L.y*wb + L.z*wcc;
        s += L.w*h;
        q += L.w*h*h + 2.f*h*lw;
      }
    s += __shfl_xor(s, 16); q += __shfl_xor(q, 16);
    s += __shfl_xor(s, 32); q += __shfl_xor(q, 32);
    if (l4 == 0) {
      atomicAdd(&sums[c], s);
      atomicAdd(&sums[512 + c], q);
    }
  }
}

// ---- finalize1: BN1 scale/shift + folded local weights w1ls = sc*w1l -------
__global__ void finalize1_kernel(const float* __restrict__ sums,
                                 const float* __restrict__ GM,
                                 const float* __restrict__ w1l,
                                 const float* __restrict__ g,
                                 const float* __restrict__ bia,
                                 float* __restrict__ ss,
                                 float* __restrict__ w1ls) {
  int c = blockIdx.x*256 + threadIdx.x;
  if (c >= 512) return;
  float w0 = w1l[c*3], w1 = w1l[c*3+1], w2 = w1l[c*3+2];
  float S = sums[c] + w0*GM[0] + w1*GM[1] + w2*GM[2];
  float Q = sums[512+c] + w0*w0*GM[3] + 2.f*w0*w1*GM[4] + 2.f*w0*w2*GM[5]
                        + w1*w1*GM[6] + 2.f*w1*w2*GM[7] + w2*w2*GM[8];
  const float invN = 1.f / (float)P_TOT;
  float mean = S * invN;
  float var  = Q * invN - mean*mean;
  float sc = g[c] * rsqrtf(var + 1e-5f);
  ss[c] = sc;
  ss[512+c] = bia[c] - mean*sc;
  w1ls[c]        = sc * w0;   // planar [3][512]
  w1ls[512 + c]  = sc * w1;
  w1ls[1024 + c] = sc * w2;
}

// ---- fold: h1u <- sc*h1u + sh (in place; BN1 affine folded into operand) ---
__global__ __launch_bounds__(256) void fold_kernel(float* __restrict__ h1u,
                                                   const float* __restrict__ ss) {
  size_t i = ((size_t)blockIdx.x*256 + threadIdx.x) * 4;   // 2048 blocks
  int c = (int)(i & 511);
  float4 v = *(float4*)(h1u + i);
  float4 sc = *(const float4*)(ss + c);
  float4 sh = *(const float4*)(ss + 512 + c);
  v.x = fmaf(v.x, sc.x, sh.x);
  v.y = fmaf(v.y, sc.y, sh.y);
  v.z = fmaf(v.z, sc.z, sh.z);
  v.w = fmaf(v.w, sc.w, sh.w);
  *(float4*)(h1u + i) = v;
}

// ============ GEMM2 (r12-exact): 128x256 tile, 8 waves (2x4), swizzled LDS ==
__global__ __launch_bounds__(512) void gemm2_kernel(
    const float* __restrict__ h1u,    // (4096, 512) f32 FOLDED
    const int* __restrict__ idx,      // (P)
    const float* __restrict__ lxyz,   // (P, 3)
    const float* __restrict__ w1ls,   // [3][512] folded local weights
    const unsigned short* __restrict__ Bw,    // (512, 512) bf16
    float* __restrict__ sums,                 // BN2 stats
    float* __restrict__ pmax,                 // (4096, 512)
    float* __restrict__ pmin)
{
  __shared__ unsigned short As[128*32];    // 8 KB
  __shared__ unsigned short Bs[256*32];    // 16 KB
  __shared__ float wl[1536];               // 6 KB
  int bx = blockIdx.x;
  int ob = bx & 1;
  size_t p0 = (size_t)(bx >> 1) * 128;
  int o0 = ob * 256;
  int t = threadIdx.x;                     // 512 threads = 8 waves
  int w = t >> 6, lane = t & 63;
  int wr = w >> 2;                         // 0..1 (p dim)
  int wc = w & 3;                          // 0..3 (o dim)
  int l15 = lane & 15, l4 = lane >> 4;
  f32x4 acc[4][4];
  f32x4 zf = {0.f, 0.f, 0.f, 0.f};
  #pragma unroll
  for (int mi = 0; mi < 4; ++mi)
    #pragma unroll
    for (int ni = 0; ni < 4; ++ni) acc[mi][ni] = zf;

  int sl = (lane & 3) ^ ((lane >> 3) & 3);   // swizzled 16B slot
  int scole = (lane & 3) * 8;
  int cA = (l4 ^ ((l15 >> 1) & 3)) * 8;      // swizzled read elem offset

  // wl: planar [3][512]
  wl[t] = w1ls[t]; wl[512 + t] = w1ls[512 + t]; wl[1024 + t] = w1ls[1024 + t];

  // A: one 16-row chunk per wave (chunk = w); per lane: row = 16w + (lane>>2)
  int arow = 16*w + (lane >> 2);
  int awoff = arow*64 + sl*16;               // swizzled As write byte offset
  const float* hptr;
  float lxr, lyr, lzr;
  {
    size_t p = p0 + arow;
    int b = (int)(p >> 15);
    int n = idx[p];
    hptr = h1u + (((size_t)b << 10) + n)*512 + scole;
    const float* lwp = lxyz + p*3;
    lxr = lwp[0]; lyr = lwp[1]; lzr = lwp[2];
  }
  // B: two 16-row chunks per wave (c = 2w+cc); pre-swizzled global source
  const unsigned short* bptr[2];
  #pragma unroll
  for (int cc = 0; cc < 2; ++cc) {
    int brow = 16*(2*w + cc) + (lane >> 2);
    bptr[cc] = Bw + (size_t)(o0 + brow)*CIN + sl*8;
  }

  float4 hv0 = *(const float4*)(hptr);
  float4 hv1 = *(const float4*)(hptr + 4);
  __syncthreads();   // wl staged

  for (int k0 = 0; k0 < CIN; k0 += 32) {
    #pragma unroll
    for (int cc = 0; cc < 2; ++cc)
      load_lds16(bptr[cc] + k0, (char*)Bs + (2*w + cc)*1024);   // linear dest
    // folded local-weight tables for channels k0+scole..+7
    int ch0 = k0 + scole;
    float4 xa = *(const float4*)(wl + ch0);
    float4 xb = *(const float4*)(wl + ch0 + 4);
    float4 ya = *(const float4*)(wl + 512 + ch0);
    float4 yb = *(const float4*)(wl + 512 + ch0 + 4);
    float4 za = *(const float4*)(wl + 1024 + ch0);
    float4 zb = *(const float4*)(wl + 1024 + ch0 + 4);
    float w0[8] = {xa.x,xa.y,xa.z,xa.w,xb.x,xb.y,xb.z,xb.w};
    float w1[8] = {ya.x,ya.y,ya.z,ya.w,yb.x,yb.y,yb.z,yb.w};
    float w2[8] = {za.x,za.y,za.z,za.w,zb.x,zb.y,zb.z,zb.w};
    {
      float fv[8] = {hv0.x, hv0.y, hv0.z, hv0.w, hv1.x, hv1.y, hv1.z, hv1.w};
      float gv[8];
      #pragma unroll
      for (int e = 0; e < 8; ++e)
        gv[e] = fmaxf(fv[e] + lxr*w0[e] + lyr*w1[e] + lzr*w2[e], 0.f);
      unsigned int rv[4];
      #pragma unroll
      for (int j = 0; j < 4; ++j) rv[j] = cvtpk(gv[2*j], gv[2*j+1]);
      *(uint4*)((char*)As + awoff) = make_uint4(rv[0], rv[1], rv[2], rv[3]);
    }
    if (k0 + 32 < CIN) {
      hv0 = *(const float4*)(hptr + k0 + 32);
      hv1 = *(const float4*)(hptr + k0 + 36);
    }
    __syncthreads();
    short8 af[4], bfr[4];
    #pragma unroll
    for (int mi = 0; mi < 4; ++mi)
      af[mi] = *(const short8*)(As + (wr*64 + mi*16 + l15)*32 + cA);
    #pragma unroll
    for (int ni = 0; ni < 4; ++ni)
      bfr[ni] = *(const short8*)(Bs + (wc*64 + ni*16 + l15)*32 + cA);
    #pragma unroll
    for (int mi = 0; mi < 4; ++mi)
      #pragma unroll
      for (int ni = 0; ni < 4; ++ni)
        acc[mi][ni] = __builtin_amdgcn_mfma_f32_16x16x32_bf16(af[mi], bfr[ni], acc[mi][ni], 0, 0, 0);
    __syncthreads();
  }

  #pragma unroll
  for (int ni = 0; ni < 4; ++ni) {
    float s = 0.f, q = 0.f;
    #pragma unroll
    for (int mi = 0; mi < 4; ++mi)
      #pragma unroll
      for (int j = 0; j < 4; ++j) { float v = acc[mi][ni][j]; s += v; q += v*v; }
    s += __shfl_xor(s, 16); q += __shfl_xor(q, 16);
    s += __shfl_xor(s, 32); q += __shfl_xor(q, 32);
    if (l4 == 0) {
      int c = o0 + wc*64 + ni*16 + l15;
      atomicAdd(&sums[c], s);
      atomicAdd(&sums[512 + c], q);
    }
  }
  #pragma unroll
  for (int ni = 0; ni < 4; ++ni) {
    #pragma unroll
    for (int h = 0; h < 2; ++h) {
      float mx = -3.4e38f, mn = 3.4e38f;
      #pragma unroll
      for (int mi = 2*h; mi < 2*h + 2; ++mi)
        #pragma unroll
        for (int j = 0; j < 4; ++j) {
          float v = acc[mi][ni][j];
          mx = fmaxf(mx, v); mn = fminf(mn, v);
        }
      mx = fmaxf(mx, __shfl_xor(mx, 16)); mn = fminf(mn, __shfl_xor(mn, 16));
      mx = fmaxf(mx, __shfl_xor(mx, 32)); mn = fminf(mn, __shfl_xor(mn, 32));
      if (l4 == 0) {
        size_t bm = (p0 >> 5) + 2*wr + h;
        int o = o0 + wc*64 + ni*16 + l15;
        pmax[bm*512 + o] = mx;
        pmin[bm*512 + o] = mn;
      }
    }
  }
}

// -------- final: BN2 finalize (per block) + affine+relu + transpose ---------
__global__ void final_transpose(const float* __restrict__ pmax,
                                const float* __restrict__ pmin,
                                const float* __restrict__ sums,
                                const float* __restrict__ g,
                                const float* __restrict__ bia,
                                float* __restrict__ out) {
  __shared__ float tile[64][65];
  __shared__ float scl[64], shl[64];
  int b = blockIdx.z, ob = blockIdx.y, mb = blockIdx.x;
  int t = threadIdx.x, tr = t >> 6, tc = t & 63;
  if (t < 64) {
    int c = ob*64 + t;
    const float invN = 1.f / (float)P_TOT;
    float mean = sums[c] * invN;
    float var  = sums[512+c] * invN - mean*mean;
    float sc = g[c] * rsqrtf(var + 1e-5f);
    scl[t] = sc;
    shl[t] = bia[c] - mean*sc;
  }
  __syncthreads();
  #pragma unroll
  for (int j = 0; j < 16; ++j) {
    int m = mb*64 + j*4 + tr;
    float sc = scl[tc], sh = shl[tc];
    size_t pi = (((size_t)b << 10) + m)*512 + ob*64 + tc;
    float v = (sc >= 0.f) ? pmax[pi] : pmin[pi];
    tile[j*4+tr][tc] = fmaxf(fmaf(v, sc, sh), 0.f);
  }
  __syncthreads();
  #pragma unroll
  for (int j = 0; j < 16; ++j) {
    int o = ob*64 + j*4 + tr;
    out[((size_t)b*512 + o)*1024 + mb*64 + tc] = tile[tc][j*4+tr];
  }
}

extern "C" void kernel_launch(void* const* d_in, const int* in_sizes, int n_in,
                              void* d_out, int out_size, void* d_ws, size_t ws_size,
                              hipStream_t stream) {
  const float* xyz   = (const float*)d_in[0];
  const float* feats = (const float*)d_in[1];
  const float* rot   = (const float*)d_in[2];
  const float* W1    = (const float*)d_in[3];
  const float* g1    = (const float*)d_in[4];
  const float* b1    = (const float*)d_in[5];
  const float* W2    = (const float*)d_in[6];
  const float* g2    = (const float*)d_in[7];
  const float* b2    = (const float*)d_in[8];
  float* out = (float*)d_out;
  char* wsb = (char*)d_ws;

  const size_t OFF_IDX    = 0;                                          // 512 KB
  const size_t OFF_LXYZ   = OFF_IDX    + (size_t)P_TOT*4;               // 1.5 MB
  const size_t OFF_FEATST = OFF_LXYZ   + (size_t)P_TOT*3*4;             // 4.2 MB
  const size_t OFF_W1F    = OFF_FEATST + (size_t)BATCH*NPTS*CIN*2;      // 512 KB
  const size_t OFF_W1L    = OFF_W1F    + (size_t)CO*512*2;              // 8 KB
  const size_t OFF_W1LS   = OFF_W1L    + 8192;                          // 8 KB
  const size_t OFF_W2B    = OFF_W1LS   + 8192;                          // 512 KB
  const size_t OFF_STATS  = OFF_W2B    + (size_t)CO*CIN*2;              // 16 KB
  const size_t OFF_L4     = OFF_STATS  + 16384;                         // 64 KB
  const size_t OFF_GM     = OFF_L4     + 65536;                         // 4 KB
  const size_t OFF_H1U    = OFF_GM     + 4096;                          // 8 MB
  const size_t OFF_PMAX   = OFF_H1U    + (size_t)BATCH*NPTS*CO*4;       // 8 MB
  const size_t OFF_PMIN   = OFF_PMAX   + (size_t)BATCH*NPTS*CO*4;       // 8 MB
  const size_t WS_NEED    = OFF_PMIN   + (size_t)BATCH*NPTS*CO*4;       // ~31 MiB

  if (ws_size < WS_NEED) return;   // diagnostic guard

  int* idx             = (int*)(wsb + OFF_IDX);
  float* lxyz          = (float*)(wsb + OFF_LXYZ);
  unsigned short* fT   = (unsigned short*)(wsb + OFF_FEATST);
  unsigned short* w1f  = (unsigned short*)(wsb + OFF_W1F);
  float* w1l           = (float*)(wsb + OFF_W1L);
  float* w1ls          = (float*)(wsb + OFF_W1LS);
  unsigned short* w2b  = (unsigned short*)(wsb + OFF_W2B);
  float* stats         = (float*)(wsb + OFF_STATS);
  float* sums1 = stats;
  float* ss1   = stats + 1024;
  float* sums2 = stats + 2048;
  float* L4            = (float*)(wsb + OFF_L4);
  float* GM            = (float*)(wsb + OFF_GM);
  float* h1u           = (float*)(wsb + OFF_H1U);
  float* pmax          = (float*)(wsb + OFF_PMAX);
  float* pmin          = (float*)(wsb + OFF_PMIN);

  hipMemsetAsync(stats, 0, 16384 + 65536 + 4096, stream);

  transpose_feats<<<dim3(NPTS/64, CIN/64, BATCH), 256, 0, stream>>>(feats, fT);
  build_weights<<<(512*512 + 255)/256, 256, 0, stream>>>(W1, W2, w1f, w1l, w2b);
  cyl_query_kernel<<<BATCH*NPTS, 64, 0, stream>>>(xyz, rot, idx, lxyz);
  scatter_kernel<<<P_TOT/256, 256, 0, stream>>>(idx, lxyz, L4, GM);

  gemm1u_kernel<<<(BATCH*NPTS/128)*4, 256, 0, stream>>>(fT, w1f, h1u, L4, w1l, sums1);
  finalize1_kernel<<<2, 256, 0, stream>>>(sums1, GM, w1l, g1, b1, ss1, w1ls);
  fold_kernel<<<(BATCH*NPTS*CO/4)/256, 256, 0, stream>>>(h1u, ss1);

  gemm2_kernel<<<(P_TOT/128)*2, 512, 0, stream>>>(h1u, idx, lxyz, w1ls, w2b,
                                                  sums2, pmax, pmin);

  final_transpose<<<dim3(NPTS/64, CO/64, BATCH), 256, 0, stream>>>(pmax, pmin,
                                                                   sums2, g2, b2, out);
}

// Round 17
// 196.716 us; speedup vs baseline: 1.1583x; 1.0042x over previous
//
#include <hip/hip_runtime.h>
#include <hip/hip_bf16.h>
#include <stdint.h>

#define BATCH 4
#define NPTS  1024
#define CIN   512
#define NS    32
#define P_TOT (BATCH*NPTS*NS)      /* 131072 */
#define CO    512
#define RADIUS_F 0.05f
#define HMIN_F  (-0.02f)
#define HMAX_F  (0.04f)

typedef __attribute__((ext_vector_type(8))) short short8;
typedef __attribute__((ext_vector_type(4))) float f32x4;

__device__ __forceinline__ unsigned short f2bf(float f) {
  unsigned int x = __float_as_uint(f);
  x = x + 0x7fffu + ((x >> 16) & 1u);   // RNE
  return (unsigned short)(x >> 16);
}
__device__ __forceinline__ float bf2f(unsigned short u) {
  return __uint_as_float(((unsigned int)u) << 16);
}
__device__ __forceinline__ unsigned int cvtpk(float lo, float hi) {
  unsigned int r;
  asm("v_cvt_pk_bf16_f32 %0, %1, %2" : "=v"(r) : "v"(lo), "v"(hi));
  return r;   // D[15:0]=bf16(lo), D[31:16]=bf16(hi), RNE
}
__device__ __forceinline__ void load_lds16(const void* g, void* l) {
  __builtin_amdgcn_global_load_lds((const __attribute__((address_space(1))) void*)g,
                                   (__attribute__((address_space(3))) void*)l, 16, 0, 0);
}

// ============ pre: transpose_feats + build_weights + cyl_query(+scatter) ====
// union grid: [0,512) transpose ; [512,1536) weights ; [1536,2560) cyl (4 seeds)
__global__ __launch_bounds__(256) void pre_kernel(
    const float* __restrict__ feats, const float* __restrict__ W1,
    const float* __restrict__ W2, const float* __restrict__ xyz,
    const float* __restrict__ rot,
    unsigned short* __restrict__ featsT, unsigned short* __restrict__ w1f,
    float* __restrict__ w1l, unsigned short* __restrict__ w2b,
    int* __restrict__ idxout, float* __restrict__ lxyz,
    float* __restrict__ L4, float* __restrict__ GMP) {
  __shared__ float tile[64][65];
  __shared__ int sidx[4][32];
  int bx = blockIdx.x;
  int t = threadIdx.x;
  if (bx < 512) {
    // ---- transpose feats (B,C,N) fp32 -> (B,N,C) bf16
    int nb = bx & 15, cb = (bx >> 4) & 7, b = bx >> 7;
    int tr = t >> 6, tc = t & 63;
    #pragma unroll
    for (int j = 0; j < 16; ++j) {
      int c = cb*64 + j*4 + tr;
      tile[j*4+tr][tc] = feats[((size_t)b*CIN + c)*NPTS + nb*64 + tc];
    }
    __syncthreads();
    #pragma unroll
    for (int j = 0; j < 16; ++j) {
      int n = nb*64 + j*4 + tr;
      featsT[((size_t)b*NPTS + n)*CIN + cb*64 + tc] = f2bf(tile[tc][j*4+tr]);
    }
  } else if (bx < 1536) {
    // ---- weight conversion
    int i = (bx - 512)*256 + t;          // 0 .. 262143
    int o = i >> 9, k = i & 511;
    w1f[i] = f2bf(W1[o*515 + 3 + k]);
    w2b[i] = f2bf(W2[i]);
    if (i < 1536) w1l[i] = W1[(i/3)*515 + (i%3)];
  } else {
    // ---- cylinder query, one seed per wave, fused scatter
    int w = t >> 6, lane = t & 63;
    int bm = (bx - 1536)*4 + w;          // b*1024 + m
    int b = bm >> 10;
    const float* ctr = xyz + (size_t)bm * 3;
    float cx = ctr[0], cy = ctr[1], cz = ctr[2];
    const float* R = rot + (size_t)bm * 9;
    float r00=R[0],r01=R[1],r02=R[2],r10=R[3],r11=R[4],r12=R[5],r20=R[6],r21=R[7],r22=R[8];
    int taken = 0;
    for (int base = 0; base < NPTS && taken < NS; base += 64) {
      int n = base + lane;
      const float* p = xyz + ((size_t)b * NPTS + n) * 3;
      float dx = p[0]-cx, dy = p[1]-cy, dz = p[2]-cz;
      float rx = dx*r00 + dy*r10 + dz*r20;
      float ry = dx*r01 + dy*r11 + dz*r21;
      float rz = dx*r02 + dy*r12 + dz*r22;
      bool ok = (ry*ry + rz*rz < RADIUS_F*RADIUS_F) && (rx > HMIN_F) && (rx < HMAX_F);
      unsigned long long bal = __ballot(ok);
      if (ok) {
        int slot = taken + __popcll(bal & ((1ull << lane) - 1ull));
        if (slot < NS) sidx[w][slot] = n;
      }
      taken += __popcll(bal);
    }
    __syncthreads();   // uniform: hit exactly once by all 4 waves
    int filled = taken < NS ? taken : NS;
    float m[9] = {0.f,0.f,0.f,0.f,0.f,0.f,0.f,0.f,0.f};
    if (lane < NS) {
      int nsel = (lane < filled) ? sidx[w][lane] : sidx[w][0];
      size_t pp = (size_t)bm * NS + lane;
      idxout[pp] = nsel;
      const float* pn = xyz + ((size_t)b * NPTS + nsel) * 3;
      float dx = pn[0]-cx, dy = pn[1]-cy, dz = pn[2]-cz;
      const float inv = 1.0f / RADIUS_F;
      float rx = (dx*r00 + dy*r10 + dz*r20) * inv;
      float ry = (dx*r01 + dy*r11 + dz*r21) * inv;
      float rz = (dx*r02 + dy*r12 + dz*r22) * inv;
      float* lw = lxyz + pp * 3;
      lw[0] = rx; lw[1] = ry; lw[2] = rz;
      float* dst = L4 + (((size_t)b << 10) + nsel)*4;
      atomicAdd(dst+0, rx); atomicAdd(dst+1, ry);
      atomicAdd(dst+2, rz); atomicAdd(dst+3, 1.0f);
      m[0]=rx; m[1]=ry; m[2]=rz;
      m[3]=rx*rx; m[4]=rx*ry; m[5]=rx*rz; m[6]=ry*ry; m[7]=ry*rz; m[8]=rz*rz;
    }
    #pragma unroll
    for (int d = 1; d < 64; d <<= 1)
      #pragma unroll
      for (int e = 0; e < 9; ++e) m[e] += __shfl_xor(m[e], d);
    if (lane < 9) atomicAdd(&GMP[(bm & 31)*12 + lane], m[lane]);
  }
}

// ============ GEMM1u: unique features x W1f^T + fused BN1 stats =============
__global__ __launch_bounds__(256) void gemm1u_kernel(
    const unsigned short* __restrict__ A,
    const unsigned short* __restrict__ Bw,
    float* __restrict__ C,
    const float* __restrict__ L4,     // (4096,4) per-u local sums + cnt
    const float* __restrict__ w1l,    // (512,3)
    float* __restrict__ sums)         // BN1 sums
{
  __shared__ unsigned short As[128*32];
  __shared__ unsigned short Bs[128*32];
  int bx = blockIdx.x;
  int ob = bx & 3;
  size_t p0 = (size_t)(bx >> 2) * 128;
  int o0 = ob * 128;
  int t = threadIdx.x;
  int w = t >> 6, lane = t & 63;
  int wr = w >> 1, wc = w & 1;
  int l15 = lane & 15, l4 = lane >> 4;
  f32x4 acc[4][4];
  f32x4 zf = {0.f, 0.f, 0.f, 0.f};
  #pragma unroll
  for (int mi = 0; mi < 4; ++mi)
    #pragma unroll
    for (int ni = 0; ni < 4; ++ni) acc[mi][ni] = zf;

  int c0 = 2*w;
  int srow = lane >> 2;
  int scole = (lane & 3) * 8;

  const unsigned short* abase[2];
  const unsigned short* bbase[2];
  #pragma unroll
  for (int cc = 0; cc < 2; ++cc) {
    int row = 16*(c0+cc) + srow;
    abase[cc] = A + (p0 + row)*(size_t)512 + scole;
    bbase[cc] = Bw + (size_t)(o0 + row)*512 + scole;
  }

  for (int k0 = 0; k0 < 512; k0 += 32) {
    #pragma unroll
    for (int cc = 0; cc < 2; ++cc) {
      int c = c0 + cc;
      load_lds16(abase[cc] + k0, (char*)As + c*1024);
      load_lds16(bbase[cc] + k0, (char*)Bs + c*1024);
    }
    __syncthreads();
    short8 af[4], bfr[4];
    #pragma unroll
    for (int mi = 0; mi < 4; ++mi)
      af[mi] = *(const short8*)(As + (wr*64 + mi*16 + l15)*32 + l4*8);
    #pragma unroll
    for (int ni = 0; ni < 4; ++ni)
      bfr[ni] = *(const short8*)(Bs + (wc*64 + ni*16 + l15)*32 + l4*8);
    #pragma unroll
    for (int mi = 0; mi < 4; ++mi)
      #pragma unroll
      for (int ni = 0; ni < 4; ++ni)
        acc[mi][ni] = __builtin_amdgcn_mfma_f32_16x16x32_bf16(af[mi], bfr[ni], acc[mi][ni], 0, 0, 0);
    __syncthreads();
  }
  // C store (fp32 h1u, RAW)
  #pragma unroll
  for (int mi = 0; mi < 4; ++mi)
    #pragma unroll
    for (int ni = 0; ni < 4; ++ni)
      #pragma unroll
      for (int j = 0; j < 4; ++j) {
        size_t p = p0 + wr*64 + mi*16 + l4*4 + j;
        int o = o0 + wc*64 + ni*16 + l15;
        C[p*512 + o] = acc[mi][ni][j];
      }
  // fused BN1 stats: S_c += cnt*h ; Q_c += cnt*h^2 + 2h*(L·w_c)
  #pragma unroll
  for (int ni = 0; ni < 4; ++ni) {
    int c = o0 + wc*64 + ni*16 + l15;
    float wa = w1l[c*3], wb = w1l[c*3+1], wcc = w1l[c*3+2];
    float s = 0.f, q = 0.f;
    #pragma unroll
    for (int mi = 0; mi < 4; ++mi)
      #pragma unroll
      for (int j = 0; j < 4; ++j) {
        size_t p = p0 + wr*64 + mi*16 + l4*4 + j;
        float4 L = *(const float4*)(L4 + p*4);
        float h = acc[mi][ni][j];
        float lw = L.x*wa + L.y*wb + L.z*wcc;
        s += L.w*h;
        q += L.w*h*h + 2.f*h*lw;
      }
    s += __shfl_xor(s, 16); q += __shfl_xor(q, 16);
    s += __shfl_xor(s, 32); q += __shfl_xor(q, 32);
    if (l4 == 0) {
      atomicAdd(&sums[c], s);
      atomicAdd(&sums[512 + c], q);
    }
  }
}

// ============ fold_fin: BN1 finalize (per block) + fold h1u in place ========
// Each block recomputes the 512-channel sc/sh table (cheap, deterministic);
// block 0 also emits w1ls for gemm2.
__global__ __launch_bounds__(256) void fold_fin_kernel(
    float* __restrict__ h1u,
    const float* __restrict__ sums,   // BN1 sums
    const float* __restrict__ GMP,    // 32 x 12 partial global moments
    const float* __restrict__ w1l,    // (512,3)
    const float* __restrict__ g,
    const float* __restrict__ bia,
    float* __restrict__ w1ls) {       // [3][512] out (block 0)
  __shared__ float ssl[1024];
  __shared__ float gms[9];
  int t = threadIdx.x;
  if (t < 9) {
    float s = 0.f;
    #pragma unroll
    for (int k = 0; k < 32; ++k) s += GMP[k*12 + t];
    gms[t] = s;
  }
  __syncthreads();
  #pragma unroll
  for (int cc = t; cc < 512; cc += 256) {
    float w0 = w1l[cc*3], w1 = w1l[cc*3+1], w2 = w1l[cc*3+2];
    float S = sums[cc] + w0*gms[0] + w1*gms[1] + w2*gms[2];
    float Q = sums[512+cc] + w0*w0*gms[3] + 2.f*w0*w1*gms[4] + 2.f*w0*w2*gms[5]
                           + w1*w1*gms[6] + 2.f*w1*w2*gms[7] + w2*w2*gms[8];
    const float invN = 1.f / (float)P_TOT;
    float mean = S * invN;
    float var  = Q * invN - mean*mean;
    float sc = g[cc] * rsqrtf(var + 1e-5f);
    ssl[cc] = sc;
    ssl[512+cc] = bia[cc] - mean*sc;
    if (blockIdx.x == 0) {
      w1ls[cc]        = sc * w0;
      w1ls[512 + cc]  = sc * w1;
      w1ls[1024 + cc] = sc * w2;
    }
  }
  __syncthreads();
  size_t i = ((size_t)blockIdx.x*256 + t) * 4;   // 2048 blocks x 1 float4
  int c = (int)(i & 511);
  float4 v = *(float4*)(h1u + i);
  v.x = fmaf(v.x, ssl[c],   ssl[512+c]);
  v.y = fmaf(v.y, ssl[c+1], ssl[512+c+1]);
  v.z = fmaf(v.z, ssl[c+2], ssl[512+c+2]);
  v.w = fmaf(v.w, ssl[c+3], ssl[512+c+3]);
  *(float4*)(h1u + i) = v;
}

// ============ GEMM2 (r16-exact): 128x256 tile, 8 waves (2x4), swizzled LDS ==
__global__ __launch_bounds__(512) void gemm2_kernel(
    const float* __restrict__ h1u,    // (4096, 512) f32 FOLDED
    const int* __restrict__ idx,      // (P)
    const float* __restrict__ lxyz,   // (P, 3)
    const float* __restrict__ w1ls,   // [3][512] folded local weights
    const unsigned short* __restrict__ Bw,    // (512, 512) bf16
    float* __restrict__ sums,                 // BN2 stats
    float* __restrict__ pmax,                 // (4096, 512)
    float* __restrict__ pmin)
{
  __shared__ unsigned short As[128*32];    // 8 KB
  __shared__ unsigned short Bs[256*32];    // 16 KB
  __shared__ float wl[1536];               // 6 KB
  int bx = blockIdx.x;
  int ob = bx & 1;
  size_t p0 = (size_t)(bx >> 1) * 128;
  int o0 = ob * 256;
  int t = threadIdx.x;                     // 512 threads = 8 waves
  int w = t >> 6, lane = t & 63;
  int wr = w >> 2;                         // 0..1 (p dim)
  int wc = w & 3;                          // 0..3 (o dim)
  int l15 = lane & 15, l4 = lane >> 4;
  f32x4 acc[4][4];
  f32x4 zf = {0.f, 0.f, 0.f, 0.f};
  #pragma unroll
  for (int mi = 0; mi < 4; ++mi)
    #pragma unroll
    for (int ni = 0; ni < 4; ++ni) acc[mi][ni] = zf;

  int sl = (lane & 3) ^ ((lane >> 3) & 3);   // swizzled 16B slot
  int scole = (lane & 3) * 8;
  int cA = (l4 ^ ((l15 >> 1) & 3)) * 8;      // swizzled read elem offset

  // wl: planar [3][512]
  wl[t] = w1ls[t]; wl[512 + t] = w1ls[512 + t]; wl[1024 + t] = w1ls[1024 + t];

  // A: one 16-row chunk per wave (chunk = w); per lane: row = 16w + (lane>>2)
  int arow = 16*w + (lane >> 2);
  int awoff = arow*64 + sl*16;               // swizzled As write byte offset
  const float* hptr;
  float lxr, lyr, lzr;
  {
    size_t p = p0 + arow;
    int b = (int)(p >> 15);
    int n = idx[p];
    hptr = h1u + (((size_t)b << 10) + n)*512 + scole;
    const float* lwp = lxyz + p*3;
    lxr = lwp[0]; lyr = lwp[1]; lzr = lwp[2];
  }
  // B: two 16-row chunks per wave (c = 2w+cc); pre-swizzled global source
  const unsigned short* bptr[2];
  #pragma unroll
  for (int cc = 0; cc < 2; ++cc) {
    int brow = 16*(2*w + cc) + (lane >> 2);
    bptr[cc] = Bw + (size_t)(o0 + brow)*CIN + sl*8;
  }

  float4 hv0 = *(const float4*)(hptr);
  float4 hv1 = *(const float4*)(hptr + 4);
  __syncthreads();   // wl staged

  for (int k0 = 0; k0 < CIN; k0 += 32) {
    #pragma unroll
    for (int cc = 0; cc < 2; ++cc)
      load_lds16(bptr[cc] + k0, (char*)Bs + (2*w + cc)*1024);   // linear dest
    // folded local-weight tables for channels k0+scole..+7
    int ch0 = k0 + scole;
    float4 xa = *(const float4*)(wl + ch0);
    float4 xb = *(const float4*)(wl + ch0 + 4);
    float4 ya = *(const float4*)(wl + 512 + ch0);
    float4 yb = *(const float4*)(wl + 512 + ch0 + 4);
    float4 za = *(const float4*)(wl + 1024 + ch0);
    float4 zb = *(const float4*)(wl + 1024 + ch0 + 4);
    float w0[8] = {xa.x,xa.y,xa.z,xa.w,xb.x,xb.y,xb.z,xb.w};
    float w1[8] = {ya.x,ya.y,ya.z,ya.w,yb.x,yb.y,yb.z,yb.w};
    float w2[8] = {za.x,za.y,za.z,za.w,zb.x,zb.y,zb.z,zb.w};
    {
      float fv[8] = {hv0.x, hv0.y, hv0.z, hv0.w, hv1.x, hv1.y, hv1.z, hv1.w};
      float gv[8];
      #pragma unroll
      for (int e = 0; e < 8; ++e)
        gv[e] = fmaxf(fv[e] + lxr*w0[e] + lyr*w1[e] + lzr*w2[e], 0.f);
      unsigned int rv[4];
      #pragma unroll
      for (int j = 0; j < 4; ++j) rv[j] = cvtpk(gv[2*j], gv[2*j+1]);
      *(uint4*)((char*)As + awoff) = make_uint4(rv[0], rv[1], rv[2], rv[3]);
    }
    if (k0 + 32 < CIN) {
      hv0 = *(const float4*)(hptr + k0 + 32);
      hv1 = *(const float4*)(hptr + k0 + 36);
    }
    __syncthreads();
    short8 af[4], bfr[4];
    #pragma unroll
    for (int mi = 0; mi < 4; ++mi)
      af[mi] = *(const short8*)(As + (wr*64 + mi*16 + l15)*32 + cA);
    #pragma unroll
    for (int ni = 0; ni < 4; ++ni)
      bfr[ni] = *(const short8*)(Bs + (wc*64 + ni*16 + l15)*32 + cA);
    #pragma unroll
    for (int mi = 0; mi < 4; ++mi)
      #pragma unroll
      for (int ni = 0; ni < 4; ++ni)
        acc[mi][ni] = __builtin_amdgcn_mfma_f32_16x16x32_bf16(af[mi], bfr[ni], acc[mi][ni], 0, 0, 0);
    __syncthreads();
  }

  #pragma unroll
  for (int ni = 0; ni < 4; ++ni) {
    float s = 0.f, q = 0.f;
    #pragma unroll
    for (int mi = 0; mi < 4; ++mi)
      #pragma unroll
      for (int j = 0; j < 4; ++j) { float v = acc[mi][ni][j]; s += v; q += v*v; }
    s += __shfl_xor(s, 16); q += __shfl_xor(q, 16);
    s += __shfl_xor(s, 32); q += __shfl_xor(q, 32);
    if (l4 == 0) {
      int c = o0 + wc*64 + ni*16 + l15;
      atomicAdd(&sums[c], s);
      atomicAdd(&sums[512 + c], q);
    }
  }
  #pragma unroll
  for (int ni = 0; ni < 4; ++ni) {
    #pragma unroll
    for (int h = 0; h < 2; ++h) {
      float mx = -3.4e38f, mn = 3.4e38f;
      #pragma unroll
      for (int mi = 2*h; mi < 2*h + 2; ++mi)
        #pragma unroll
        for (int j = 0; j < 4; ++j) {
          float v = acc[mi][ni][j];
          mx = fmaxf(mx, v); mn = fminf(mn, v);
        }
      mx = fmaxf(mx, __shfl_xor(mx, 16)); mn = fminf(mn, __shfl_xor(mn, 16));
      mx = fmaxf(mx, __shfl_xor(mx, 32)); mn = fminf(mn, __shfl_xor(mn, 32));
      if (l4 == 0) {
        size_t bm = (p0 >> 5) + 2*wr + h;
        int o = o0 + wc*64 + ni*16 + l15;
        pmax[bm*512 + o] = mx;
        pmin[bm*512 + o] = mn;
      }
    }
  }
}

// -------- final: BN2 finalize (per block) + affine+relu + transpose ---------
__global__ void final_transpose(const float* __restrict__ pmax,
                                const float* __restrict__ pmin,
                                const float* __restrict__ sums,
                                const float* __restrict__ g,
                                const float* __restrict__ bia,
                                float* __restrict__ out) {
  __shared__ float tile[64][65];
  __shared__ float scl[64], shl[64];
  int b = blockIdx.z, ob = blockIdx.y, mb = blockIdx.x;
  int t = threadIdx.x, tr = t >> 6, tc = t & 63;
  if (t < 64) {
    int c = ob*64 + t;
    const float invN = 1.f / (float)P_TOT;
    float mean = sums[c] * invN;
    float var  = sums[512+c] * invN - mean*mean;
    float sc = g[c] * rsqrtf(var + 1e-5f);
    scl[t] = sc;
    shl[t] = bia[c] - mean*sc;
  }
  __syncthreads();
  #pragma unroll
  for (int j = 0; j < 16; ++j) {
    int m = mb*64 + j*4 + tr;
    float sc = scl[tc], sh = shl[tc];
    size_t pi = (((size_t)b << 10) + m)*512 + ob*64 + tc;
    float v = (sc >= 0.f) ? pmax[pi] : pmin[pi];
    tile[j*4+tr][tc] = fmaxf(fmaf(v, sc, sh), 0.f);
  }
  __syncthreads();
  #pragma unroll
  for (int j = 0; j < 16; ++j) {
    int o = ob*64 + j*4 + tr;
    out[((size_t)b*512 + o)*1024 + mb*64 + tc] = tile[tc][j*4+tr];
  }
}

extern "C" void kernel_launch(void* const* d_in, const int* in_sizes, int n_in,
                              void* d_out, int out_size, void* d_ws, size_t ws_size,
                              hipStream_t stream) {
  const float* xyz   = (const float*)d_in[0];
  const float* feats = (const float*)d_in[1];
  const float* rot   = (const float*)d_in[2];
  const float* W1    = (const float*)d_in[3];
  const float* g1    = (const float*)d_in[4];
  const float* b1    = (const float*)d_in[5];
  const float* W2    = (const float*)d_in[6];
  const float* g2    = (const float*)d_in[7];
  const float* b2    = (const float*)d_in[8];
  float* out = (float*)d_out;
  char* wsb = (char*)d_ws;

  const size_t OFF_IDX    = 0;                                          // 512 KB
  const size_t OFF_LXYZ   = OFF_IDX    + (size_t)P_TOT*4;               // 1.5 MB
  const size_t OFF_FEATST = OFF_LXYZ   + (size_t)P_TOT*3*4;             // 4.2 MB
  const size_t OFF_W1F    = OFF_FEATST + (size_t)BATCH*NPTS*CIN*2;      // 512 KB
  const size_t OFF_W1L    = OFF_W1F    + (size_t)CO*512*2;              // 8 KB
  const size_t OFF_W1LS   = OFF_W1L    + 8192;                          // 8 KB
  const size_t OFF_W2B    = OFF_W1LS   + 8192;                          // 512 KB
  const size_t OFF_STATS  = OFF_W2B    + (size_t)CO*CIN*2;              // 16 KB
  const size_t OFF_L4     = OFF_STATS  + 16384;                         // 64 KB
  const size_t OFF_GMP    = OFF_L4     + 65536;                         // 4 KB (32x12)
  const size_t OFF_H1U    = OFF_GMP    + 4096;                          // 8 MB
  const size_t OFF_PMAX   = OFF_H1U    + (size_t)BATCH*NPTS*CO*4;       // 8 MB
  const size_t OFF_PMIN   = OFF_PMAX   + (size_t)BATCH*NPTS*CO*4;       // 8 MB
  const size_t WS_NEED    = OFF_PMIN   + (size_t)BATCH*NPTS*CO*4;       // ~31 MiB

  if (ws_size < WS_NEED) return;   // diagnostic guard

  int* idx             = (int*)(wsb + OFF_IDX);
  float* lxyz          = (float*)(wsb + OFF_LXYZ);
  unsigned short* fT   = (unsigned short*)(wsb + OFF_FEATST);
  unsigned short* w1f  = (unsigned short*)(wsb + OFF_W1F);
  float* w1l           = (float*)(wsb + OFF_W1L);
  float* w1ls          = (float*)(wsb + OFF_W1LS);
  unsigned short* w2b  = (unsigned short*)(wsb + OFF_W2B);
  float* stats         = (float*)(wsb + OFF_STATS);
  float* sums1 = stats;
  float* sums2 = stats + 2048;
  float* L4            = (float*)(wsb + OFF_L4);
  float* GMP           = (float*)(wsb + OFF_GMP);
  float* h1u           = (float*)(wsb + OFF_H1U);
  float* pmax          = (float*)(wsb + OFF_PMAX);
  float* pmin          = (float*)(wsb + OFF_PMIN);

  // zero stats + L4 + GMP (contiguous)
  hipMemsetAsync(stats, 0, 16384 + 65536 + 4096, stream);

  pre_kernel<<<2560, 256, 0, stream>>>(feats, W1, W2, xyz, rot,
                                       fT, w1f, w1l, w2b, idx, lxyz, L4, GMP);

  gemm1u_kernel<<<(BATCH*NPTS/128)*4, 256, 0, stream>>>(fT, w1f, h1u, L4, w1l, sums1);

  fold_fin_kernel<<<(BATCH*NPTS*CO/4)/256, 256, 0, stream>>>(h1u, sums1, GMP,
                                                             w1l, g1, b1, w1ls);

  gemm2_kernel<<<(P_TOT/128)*2, 512, 0, stream>>>(h1u, idx, lxyz, w1ls, w2b,
                                                  sums2, pmax, pmin);

  final_transpose<<<dim3(NPTS/64, CO/64, BATCH), 256, 0, stream>>>(pmax, pmin,
                                                                   sums2, g2, b2, out);
}

// Round 18
// 193.942 us; speedup vs baseline: 1.1749x; 1.0143x over previous
//
#include <hip/hip_runtime.h>
#include <hip/hip_bf16.h>
#include <stdint.h>

#define BATCH 4
#define NPTS  1024
#define CIN   512
#define NS    32
#define P_TOT (BATCH*NPTS*NS)      /* 131072 */
#define CO    512
#define RADIUS_F 0.05f
#define HMIN_F  (-0.02f)
#define HMAX_F  (0.04f)

typedef __attribute__((ext_vector_type(8))) short short8;
typedef __attribute__((ext_vector_type(4))) float f32x4;

__device__ __forceinline__ unsigned short f2bf(float f) {
  unsigned int x = __float_as_uint(f);
  x = x + 0x7fffu + ((x >> 16) & 1u);   // RNE
  return (unsigned short)(x >> 16);
}
__device__ __forceinline__ float bf2f(unsigned short u) {
  return __uint_as_float(((unsigned int)u) << 16);
}
__device__ __forceinline__ unsigned int cvtpk(float lo, float hi) {
  unsigned int r;
  asm("v_cvt_pk_bf16_f32 %0, %1, %2" : "=v"(r) : "v"(lo), "v"(hi));
  return r;   // D[15:0]=bf16(lo), D[31:16]=bf16(hi), RNE
}
__device__ __forceinline__ void load_lds16(const void* g, void* l) {
  __builtin_amdgcn_global_load_lds((const __attribute__((address_space(1))) void*)g,
                                   (__attribute__((address_space(3))) void*)l, 16, 0, 0);
}

// ============ pre: transpose_feats + build_weights + cyl_query(+scatter) ====
// union grid: [0,512) transpose ; [512,1536) weights ; [1536,2560) cyl (4 seeds)
__global__ __launch_bounds__(256) void pre_kernel(
    const float* __restrict__ feats, const float* __restrict__ W1,
    const float* __restrict__ W2, const float* __restrict__ xyz,
    const float* __restrict__ rot,
    unsigned short* __restrict__ featsT, unsigned short* __restrict__ w1f,
    float* __restrict__ w1l, unsigned short* __restrict__ w2b,
    int* __restrict__ idxout, float* __restrict__ lxyz,
    float* __restrict__ L4, float* __restrict__ GMP) {
  __shared__ float tile[64][65];
  __shared__ int sidx[4][32];
  int bx = blockIdx.x;
  int t = threadIdx.x;
  if (bx < 512) {
    // ---- transpose feats (B,C,N) fp32 -> (B,N,C) bf16
    int nb = bx & 15, cb = (bx >> 4) & 7, b = bx >> 7;
    int tr = t >> 6, tc = t & 63;
    #pragma unroll
    for (int j = 0; j < 16; ++j) {
      int c = cb*64 + j*4 + tr;
      tile[j*4+tr][tc] = feats[((size_t)b*CIN + c)*NPTS + nb*64 + tc];
    }
    __syncthreads();
    #pragma unroll
    for (int j = 0; j < 16; ++j) {
      int n = nb*64 + j*4 + tr;
      featsT[((size_t)b*NPTS + n)*CIN + cb*64 + tc] = f2bf(tile[tc][j*4+tr]);
    }
  } else if (bx < 1536) {
    // ---- weight conversion
    int i = (bx - 512)*256 + t;          // 0 .. 262143
    int o = i >> 9, k = i & 511;
    w1f[i] = f2bf(W1[o*515 + 3 + k]);
    w2b[i] = f2bf(W2[i]);
    if (i < 1536) w1l[i] = W1[(i/3)*515 + (i%3)];
  } else {
    // ---- cylinder query, one seed per wave, fused scatter
    int w = t >> 6, lane = t & 63;
    int bm = (bx - 1536)*4 + w;          // b*1024 + m
    int b = bm >> 10;
    const float* ctr = xyz + (size_t)bm * 3;
    float cx = ctr[0], cy = ctr[1], cz = ctr[2];
    const float* R = rot + (size_t)bm * 9;
    float r00=R[0],r01=R[1],r02=R[2],r10=R[3],r11=R[4],r12=R[5],r20=R[6],r21=R[7],r22=R[8];
    int taken = 0;
    for (int base = 0; base < NPTS && taken < NS; base += 64) {
      int n = base + lane;
      const float* p = xyz + ((size_t)b * NPTS + n) * 3;
      float dx = p[0]-cx, dy = p[1]-cy, dz = p[2]-cz;
      float rx = dx*r00 + dy*r10 + dz*r20;
      float ry = dx*r01 + dy*r11 + dz*r21;
      float rz = dx*r02 + dy*r12 + dz*r22;
      bool ok = (ry*ry + rz*rz < RADIUS_F*RADIUS_F) && (rx > HMIN_F) && (rx < HMAX_F);
      unsigned long long bal = __ballot(ok);
      if (ok) {
        int slot = taken + __popcll(bal & ((1ull << lane) - 1ull));
        if (slot < NS) sidx[w][slot] = n;
      }
      taken += __popcll(bal);
    }
    __syncthreads();   // uniform: hit exactly once by all 4 waves
    int filled = taken < NS ? taken : NS;
    float m[9] = {0.f,0.f,0.f,0.f,0.f,0.f,0.f,0.f,0.f};
    if (lane < NS) {
      int nsel = (lane < filled) ? sidx[w][lane] : sidx[w][0];
      size_t pp = (size_t)bm * NS + lane;
      idxout[pp] = nsel;
      const float* pn = xyz + ((size_t)b * NPTS + nsel) * 3;
      float dx = pn[0]-cx, dy = pn[1]-cy, dz = pn[2]-cz;
      const float inv = 1.0f / RADIUS_F;
      float rx = (dx*r00 + dy*r10 + dz*r20) * inv;
      float ry = (dx*r01 + dy*r11 + dz*r21) * inv;
      float rz = (dx*r02 + dy*r12 + dz*r22) * inv;
      float* lw = lxyz + pp * 3;
      lw[0] = rx; lw[1] = ry; lw[2] = rz;
      float* dst = L4 + (((size_t)b << 10) + nsel)*4;
      atomicAdd(dst+0, rx); atomicAdd(dst+1, ry);
      atomicAdd(dst+2, rz); atomicAdd(dst+3, 1.0f);
      m[0]=rx; m[1]=ry; m[2]=rz;
      m[3]=rx*rx; m[4]=rx*ry; m[5]=rx*rz; m[6]=ry*ry; m[7]=ry*rz; m[8]=rz*rz;
    }
    #pragma unroll
    for (int d = 1; d < 64; d <<= 1)
      #pragma unroll
      for (int e = 0; e < 9; ++e) m[e] += __shfl_xor(m[e], d);
    if (lane < 9) atomicAdd(&GMP[(bm & 31)*12 + lane], m[lane]);
  }
}

// ============ GEMM1u v2: 64x64 tile, 512 blocks, fused BN1 stats ============
// 4 waves as 2x2; per-wave 32x32 (acc[2][2]). 8 KB LDS -> high occupancy.
__global__ __launch_bounds__(256) void gemm1u_kernel(
    const unsigned short* __restrict__ A,     // (4096, 512) fT
    const unsigned short* __restrict__ Bw,    // (512, 512) w1f
    float* __restrict__ C,                    // (4096, 512) h1u RAW
    const float* __restrict__ L4,             // (4096,4)
    const float* __restrict__ w1l,            // (512,3)
    float* __restrict__ sums)                 // BN1 sums
{
  __shared__ unsigned short As[64*32];   // 4 KB
  __shared__ unsigned short Bs[64*32];   // 4 KB
  int bx = blockIdx.x;                   // 512 = 64 p-tiles x 8 o-tiles
  int ob = bx & 7;
  size_t p0 = (size_t)(bx >> 3) * 64;
  int o0 = ob * 64;
  int t = threadIdx.x;
  int w = t >> 6, lane = t & 63;
  int wr = w >> 1, wc = w & 1;
  int l15 = lane & 15, l4 = lane >> 4;
  f32x4 acc[2][2];
  f32x4 zf = {0.f, 0.f, 0.f, 0.f};
  #pragma unroll
  for (int mi = 0; mi < 2; ++mi)
    #pragma unroll
    for (int ni = 0; ni < 2; ++ni) acc[mi][ni] = zf;

  // staging: wave w covers rows w*16..w*16+15 of each tile; lane -> (row, slot)
  int srow = t >> 2;            // 0..63
  int scol = (t & 3) * 8;
  const unsigned short* abase = A + (p0 + srow)*(size_t)512 + scol;
  const unsigned short* bbase = Bw + (size_t)(o0 + srow)*512 + scol;

  for (int k0 = 0; k0 < 512; k0 += 32) {
    load_lds16(abase + k0, (char*)As + w*1024);   // wave-uniform dest base
    load_lds16(bbase + k0, (char*)Bs + w*1024);
    __syncthreads();
    short8 af[2], bfr[2];
    #pragma unroll
    for (int mi = 0; mi < 2; ++mi)
      af[mi] = *(const short8*)(As + (wr*32 + mi*16 + l15)*32 + l4*8);
    #pragma unroll
    for (int ni = 0; ni < 2; ++ni)
      bfr[ni] = *(const short8*)(Bs + (wc*32 + ni*16 + l15)*32 + l4*8);
    #pragma unroll
    for (int mi = 0; mi < 2; ++mi)
      #pragma unroll
      for (int ni = 0; ni < 2; ++ni)
        acc[mi][ni] = __builtin_amdgcn_mfma_f32_16x16x32_bf16(af[mi], bfr[ni], acc[mi][ni], 0, 0, 0);
    __syncthreads();
  }
  // C store (fp32 h1u, RAW)
  #pragma unroll
  for (int mi = 0; mi < 2; ++mi)
    #pragma unroll
    for (int ni = 0; ni < 2; ++ni)
      #pragma unroll
      for (int j = 0; j < 4; ++j) {
        size_t p = p0 + wr*32 + mi*16 + l4*4 + j;
        int o = o0 + wc*32 + ni*16 + l15;
        C[p*512 + o] = acc[mi][ni][j];
      }
  // fused BN1 stats: S_c += cnt*h ; Q_c += cnt*h^2 + 2h*(L·w_c)
  #pragma unroll
  for (int ni = 0; ni < 2; ++ni) {
    int c = o0 + wc*32 + ni*16 + l15;
    float wa = w1l[c*3], wb = w1l[c*3+1], wcc = w1l[c*3+2];
    float s = 0.f, q = 0.f;
    #pragma unroll
    for (int mi = 0; mi < 2; ++mi)
      #pragma unroll
      for (int j = 0; j < 4; ++j) {
        size_t p = p0 + wr*32 + mi*16 + l4*4 + j;
        float4 L = *(const float4*)(L4 + p*4);
        float h = acc[mi][ni][j];
        float lw = L.x*wa + L.y*wb + L.z*wcc;
        s += L.w*h;
        q += L.w*h*h + 2.f*h*lw;
      }
    s += __shfl_xor(s, 16); q += __shfl_xor(q, 16);
    s += __shfl_xor(s, 32); q += __shfl_xor(q, 32);
    if (l4 == 0) {
      atomicAdd(&sums[c], s);
      atomicAdd(&sums[512 + c], q);
    }
  }
}

// ============ fold_fin: BN1 finalize (per block) + fold h1u in place ========
__global__ __launch_bounds__(256) void fold_fin_kernel(
    float* __restrict__ h1u,
    const float* __restrict__ sums,   // BN1 sums
    const float* __restrict__ GMP,    // 32 x 12 partial global moments
    const float* __restrict__ w1l,    // (512,3)
    const float* __restrict__ g,
    const float* __restrict__ bia,
    float* __restrict__ w1ls) {       // [3][512] out (block 0)
  __shared__ float ssl[1024];
  __shared__ float gms[9];
  int t = threadIdx.x;
  if (t < 9) {
    float s = 0.f;
    #pragma unroll
    for (int k = 0; k < 32; ++k) s += GMP[k*12 + t];
    gms[t] = s;
  }
  __syncthreads();
  #pragma unroll
  for (int cc = t; cc < 512; cc += 256) {
    float w0 = w1l[cc*3], w1 = w1l[cc*3+1], w2 = w1l[cc*3+2];
    float S = sums[cc] + w0*gms[0] + w1*gms[1] + w2*gms[2];
    float Q = sums[512+cc] + w0*w0*gms[3] + 2.f*w0*w1*gms[4] + 2.f*w0*w2*gms[5]
                           + w1*w1*gms[6] + 2.f*w1*w2*gms[7] + w2*w2*gms[8];
    const float invN = 1.f / (float)P_TOT;
    float mean = S * invN;
    float var  = Q * invN - mean*mean;
    float sc = g[cc] * rsqrtf(var + 1e-5f);
    ssl[cc] = sc;
    ssl[512+cc] = bia[cc] - mean*sc;
    if (blockIdx.x == 0) {
      w1ls[cc]        = sc * w0;
      w1ls[512 + cc]  = sc * w1;
      w1ls[1024 + cc] = sc * w2;
    }
  }
  __syncthreads();
  size_t i = ((size_t)blockIdx.x*256 + t) * 4;   // 2048 blocks x 1 float4
  int c = (int)(i & 511);
  float4 v = *(float4*)(h1u + i);
  v.x = fmaf(v.x, ssl[c],   ssl[512+c]);
  v.y = fmaf(v.y, ssl[c+1], ssl[512+c+1]);
  v.z = fmaf(v.z, ssl[c+2], ssl[512+c+2]);
  v.w = fmaf(v.w, ssl[c+3], ssl[512+c+3]);
  *(float4*)(h1u + i) = v;
}

// ============ GEMM2 (r16-exact): 128x256 tile, 8 waves (2x4), swizzled LDS ==
__global__ __launch_bounds__(512) void gemm2_kernel(
    const float* __restrict__ h1u,    // (4096, 512) f32 FOLDED
    const int* __restrict__ idx,      // (P)
    const float* __restrict__ lxyz,   // (P, 3)
    const float* __restrict__ w1ls,   // [3][512] folded local weights
    const unsigned short* __restrict__ Bw,    // (512, 512) bf16
    float* __restrict__ sums,                 // BN2 stats
    float* __restrict__ pmax,                 // (4096, 512)
    float* __restrict__ pmin)
{
  __shared__ unsigned short As[128*32];    // 8 KB
  __shared__ unsigned short Bs[256*32];    // 16 KB
  __shared__ float wl[1536];               // 6 KB
  int bx = blockIdx.x;
  int ob = bx & 1;
  size_t p0 = (size_t)(bx >> 1) * 128;
  int o0 = ob * 256;
  int t = threadIdx.x;                     // 512 threads = 8 waves
  int w = t >> 6, lane = t & 63;
  int wr = w >> 2;                         // 0..1 (p dim)
  int wc = w & 3;                          // 0..3 (o dim)
  int l15 = lane & 15, l4 = lane >> 4;
  f32x4 acc[4][4];
  f32x4 zf = {0.f, 0.f, 0.f, 0.f};
  #pragma unroll
  for (int mi = 0; mi < 4; ++mi)
    #pragma unroll
    for (int ni = 0; ni < 4; ++ni) acc[mi][ni] = zf;

  int sl = (lane & 3) ^ ((lane >> 3) & 3);   // swizzled 16B slot
  int scole = (lane & 3) * 8;
  int cA = (l4 ^ ((l15 >> 1) & 3)) * 8;      // swizzled read elem offset

  // wl: planar [3][512]
  wl[t] = w1ls[t]; wl[512 + t] = w1ls[512 + t]; wl[1024 + t] = w1ls[1024 + t];

  // A: one 16-row chunk per wave (chunk = w); per lane: row = 16w + (lane>>2)
  int arow = 16*w + (lane >> 2);
  int awoff = arow*64 + sl*16;               // swizzled As write byte offset
  const float* hptr;
  float lxr, lyr, lzr;
  {
    size_t p = p0 + arow;
    int b = (int)(p >> 15);
    int n = idx[p];
    hptr = h1u + (((size_t)b << 10) + n)*512 + scole;
    const float* lwp = lxyz + p*3;
    lxr = lwp[0]; lyr = lwp[1]; lzr = lwp[2];
  }
  // B: two 16-row chunks per wave (c = 2w+cc); pre-swizzled global source
  const unsigned short* bptr[2];
  #pragma unroll
  for (int cc = 0; cc < 2; ++cc) {
    int brow = 16*(2*w + cc) + (lane >> 2);
    bptr[cc] = Bw + (size_t)(o0 + brow)*CIN + sl*8;
  }

  float4 hv0 = *(const float4*)(hptr);
  float4 hv1 = *(const float4*)(hptr + 4);
  __syncthreads();   // wl staged

  for (int k0 = 0; k0 < CIN; k0 += 32) {
    #pragma unroll
    for (int cc = 0; cc < 2; ++cc)
      load_lds16(bptr[cc] + k0, (char*)Bs + (2*w + cc)*1024);   // linear dest
    // folded local-weight tables for channels k0+scole..+7
    int ch0 = k0 + scole;
    float4 xa = *(const float4*)(wl + ch0);
    float4 xb = *(const float4*)(wl + ch0 + 4);
    float4 ya = *(const float4*)(wl + 512 + ch0);
    float4 yb = *(const float4*)(wl + 512 + ch0 + 4);
    float4 za = *(const float4*)(wl + 1024 + ch0);
    float4 zb = *(const float4*)(wl + 1024 + ch0 + 4);
    float w0[8] = {xa.x,xa.y,xa.z,xa.w,xb.x,xb.y,xb.z,xb.w};
    float w1[8] = {ya.x,ya.y,ya.z,ya.w,yb.x,yb.y,yb.z,yb.w};
    float w2[8] = {za.x,za.y,za.z,za.w,zb.x,zb.y,zb.z,zb.w};
    {
      float fv[8] = {hv0.x, hv0.y, hv0.z, hv0.w, hv1.x, hv1.y, hv1.z, hv1.w};
      float gv[8];
      #pragma unroll
      for (int e = 0; e < 8; ++e)
        gv[e] = fmaxf(fv[e] + lxr*w0[e] + lyr*w1[e] + lzr*w2[e], 0.f);
      unsigned int rv[4];
      #pragma unroll
      for (int j = 0; j < 4; ++j) rv[j] = cvtpk(gv[2*j], gv[2*j+1]);
      *(uint4*)((char*)As + awoff) = make_uint4(rv[0], rv[1], rv[2], rv[3]);
    }
    if (k0 + 32 < CIN) {
      hv0 = *(const float4*)(hptr + k0 + 32);
      hv1 = *(const float4*)(hptr + k0 + 36);
    }
    __syncthreads();
    short8 af[4], bfr[4];
    #pragma unroll
    for (int mi = 0; mi < 4; ++mi)
      af[mi] = *(const short8*)(As + (wr*64 + mi*16 + l15)*32 + cA);
    #pragma unroll
    for (int ni = 0; ni < 4; ++ni)
      bfr[ni] = *(const short8*)(Bs + (wc*64 + ni*16 + l15)*32 + cA);
    #pragma unroll
    for (int mi = 0; mi < 4; ++mi)
      #pragma unroll
      for (int ni = 0; ni < 4; ++ni)
        acc[mi][ni] = __builtin_amdgcn_mfma_f32_16x16x32_bf16(af[mi], bfr[ni], acc[mi][ni], 0, 0, 0);
    __syncthreads();
  }

  #pragma unroll
  for (int ni = 0; ni < 4; ++ni) {
    float s = 0.f, q = 0.f;
    #pragma unroll
    for (int mi = 0; mi < 4; ++mi)
      #pragma unroll
      for (int j = 0; j < 4; ++j) { float v = acc[mi][ni][j]; s += v; q += v*v; }
    s += __shfl_xor(s, 16); q += __shfl_xor(q, 16);
    s += __shfl_xor(s, 32); q += __shfl_xor(q, 32);
    if (l4 == 0) {
      int c = o0 + wc*64 + ni*16 + l15;
      atomicAdd(&sums[c], s);
      atomicAdd(&sums[512 + c], q);
    }
  }
  #pragma unroll
  for (int ni = 0; ni < 4; ++ni) {
    #pragma unroll
    for (int h = 0; h < 2; ++h) {
      float mx = -3.4e38f, mn = 3.4e38f;
      #pragma unroll
      for (int mi = 2*h; mi < 2*h + 2; ++mi)
        #pragma unroll
        for (int j = 0; j < 4; ++j) {
          float v = acc[mi][ni][j];
          mx = fmaxf(mx, v); mn = fminf(mn, v);
        }
      mx = fmaxf(mx, __shfl_xor(mx, 16)); mn = fminf(mn, __shfl_xor(mn, 16));
      mx = fmaxf(mx, __shfl_xor(mx, 32)); mn = fminf(mn, __shfl_xor(mn, 32));
      if (l4 == 0) {
        size_t bm = (p0 >> 5) + 2*wr + h;
        int o = o0 + wc*64 + ni*16 + l15;
        pmax[bm*512 + o] = mx;
        pmin[bm*512 + o] = mn;
      }
    }
  }
}

// -------- final: BN2 finalize (per block) + affine+relu + transpose ---------
__global__ void final_transpose(const float* __restrict__ pmax,
                                const float* __restrict__ pmin,
                                const float* __restrict__ sums,
                                const float* __restrict__ g,
                                const float* __restrict__ bia,
                                float* __restrict__ out) {
  __shared__ float tile[64][65];
  __shared__ float scl[64], shl[64];
  int b = blockIdx.z, ob = blockIdx.y, mb = blockIdx.x;
  int t = threadIdx.x, tr = t >> 6, tc = t & 63;
  if (t < 64) {
    int c = ob*64 + t;
    const float invN = 1.f / (float)P_TOT;
    float mean = sums[c] * invN;
    float var  = sums[512+c] * invN - mean*mean;
    float sc = g[c] * rsqrtf(var + 1e-5f);
    scl[t] = sc;
    shl[t] = bia[c] - mean*sc;
  }
  __syncthreads();
  #pragma unroll
  for (int j = 0; j < 16; ++j) {
    int m = mb*64 + j*4 + tr;
    float sc = scl[tc], sh = shl[tc];
    size_t pi = (((size_t)b << 10) + m)*512 + ob*64 + tc;
    float v = (sc >= 0.f) ? pmax[pi] : pmin[pi];
    tile[j*4+tr][tc] = fmaxf(fmaf(v, sc, sh), 0.f);
  }
  __syncthreads();
  #pragma unroll
  for (int j = 0; j < 16; ++j) {
    int o = ob*64 + j*4 + tr;
    out[((size_t)b*512 + o)*1024 + mb*64 + tc] = tile[tc][j*4+tr];
  }
}

extern "C" void kernel_launch(void* const* d_in, const int* in_sizes, int n_in,
                              void* d_out, int out_size, void* d_ws, size_t ws_size,
                              hipStream_t stream) {
  const float* xyz   = (const float*)d_in[0];
  const float* feats = (const float*)d_in[1];
  const float* rot   = (const float*)d_in[2];
  const float* W1    = (const float*)d_in[3];
  const float* g1    = (const float*)d_in[4];
  const float* b1    = (const float*)d_in[5];
  const float* W2    = (const float*)d_in[6];
  const float* g2    = (const float*)d_in[7];
  const float* b2    = (const float*)d_in[8];
  float* out = (float*)d_out;
  char* wsb = (char*)d_ws;

  const size_t OFF_IDX    = 0;                                          // 512 KB
  const size_t OFF_LXYZ   = OFF_IDX    + (size_t)P_TOT*4;               // 1.5 MB
  const size_t OFF_FEATST = OFF_LXYZ   + (size_t)P_TOT*3*4;             // 4.2 MB
  const size_t OFF_W1F    = OFF_FEATST + (size_t)BATCH*NPTS*CIN*2;      // 512 KB
  const size_t OFF_W1L    = OFF_W1F    + (size_t)CO*512*2;              // 8 KB
  const size_t OFF_W1LS   = OFF_W1L    + 8192;                          // 8 KB
  const size_t OFF_W2B    = OFF_W1LS   + 8192;                          // 512 KB
  const size_t OFF_STATS  = OFF_W2B    + (size_t)CO*CIN*2;              // 16 KB
  const size_t OFF_L4     = OFF_STATS  + 16384;                         // 64 KB
  const size_t OFF_GMP    = OFF_L4     + 65536;                         // 4 KB (32x12)
  const size_t OFF_H1U    = OFF_GMP    + 4096;                          // 8 MB
  const size_t OFF_PMAX   = OFF_H1U    + (size_t)BATCH*NPTS*CO*4;       // 8 MB
  const size_t OFF_PMIN   = OFF_PMAX   + (size_t)BATCH*NPTS*CO*4;       // 8 MB
  const size_t WS_NEED    = OFF_PMIN   + (size_t)BATCH*NPTS*CO*4;       // ~31 MiB

  if (ws_size < WS_NEED) return;   // diagnostic guard

  int* idx             = (int*)(wsb + OFF_IDX);
  float* lxyz          = (float*)(wsb + OFF_LXYZ);
  unsigned short* fT   = (unsigned short*)(wsb + OFF_FEATST);
  unsigned short* w1f  = (unsigned short*)(wsb + OFF_W1F);
  float* w1l           = (float*)(wsb + OFF_W1L);
  float* w1ls          = (float*)(wsb + OFF_W1LS);
  unsigned short* w2b  = (unsigned short*)(wsb + OFF_W2B);
  float* stats         = (float*)(wsb + OFF_STATS);
  float* sums1 = stats;
  float* sums2 = stats + 2048;
  float* L4            = (float*)(wsb + OFF_L4);
  float* GMP           = (float*)(wsb + OFF_GMP);
  float* h1u           = (float*)(wsb + OFF_H1U);
  float* pmax          = (float*)(wsb + OFF_PMAX);
  float* pmin          = (float*)(wsb + OFF_PMIN);

  // zero stats + L4 + GMP (contiguous)
  hipMemsetAsync(stats, 0, 16384 + 65536 + 4096, stream);

  pre_kernel<<<2560, 256, 0, stream>>>(feats, W1, W2, xyz, rot,
                                       fT, w1f, w1l, w2b, idx, lxyz, L4, GMP);

  gemm1u_kernel<<<512, 256, 0, stream>>>(fT, w1f, h1u, L4, w1l, sums1);

  fold_fin_kernel<<<(BATCH*NPTS*CO/4)/256, 256, 0, stream>>>(h1u, sums1, GMP,
                                                             w1l, g1, b1, w1ls);

  gemm2_kernel<<<(P_TOT/128)*2, 512, 0, stream>>>(h1u, idx, lxyz, w1ls, w2b,
                                                  sums2, pmax, pmin);

  final_transpose<<<dim3(NPTS/64, CO/64, BATCH), 256, 0, stream>>>(pmax, pmin,
                                                                   sums2, g2, b2, out);
}